// Round 8
// baseline (381.957 us; speedup 1.0000x reference)
//
#include <hip/hip_runtime.h>
#include <math.h>

// ---------------------------------------------------------------------------
// Moondream3Attention on MI355X (gfx950)
// T=2048, DIM=2048, H=32, HD=64, ROT=32, QKV_DIM=6144
// Pipeline (all-bf16 matmul datapath):  [R14: 128x192 2-block/CU QKV GEMM]
//   0) cvt3: hidden->hb, Wqkv->wqb, Wout->wob (fp32->bf16, one launch)
//   1) qkv GEMM: 128x192 tile, BK=64, 256 thr (2x2 waves, 64x96/wave),
//      4-phase counted-vmcnt(7) schedule, LDS 80KiB -> 2 blocks/CU,
//      grid 32x16 = 512 blocks = exactly 2/CU (full fill + inter-block
//      overlap; R6 analysis: LDS pipe is the binding resource and the
//      1-block/CU 256^2 tile serialized LDS vs MFMA at every barrier).
//   2) tok = gelu(P) @ [tau_wq;tau_wv]^T   (split-K + atomics)
//   3) qkv_process (ushort8-vectorized): tau gating + RoPE;
//      V packed fragment-ordered: vpk[h][sb32][nt][quad][m][8]
//   4) attn_fa: s-split MAX-FREE flash attention, 1280 blocks
//   5) attn_merge: O = sum_c O~_c / sum_c l_c -> attnb bf16
//   6) out = attnb @ wob^T + bout (64x64 tile, 1024 blocks, plain R4 form;
//      R6 A/B: lgkm/setprio discipline null at 4 blocks/CU -> reverted)
// Workspace (94,371,840 B), liveness-overlapped (unchanged from R10).
// ---------------------------------------------------------------------------

typedef __bf16 bf16x8 __attribute__((ext_vector_type(8)));
typedef float floatx4 __attribute__((ext_vector_type(4)));
typedef unsigned short ushort8v __attribute__((ext_vector_type(8)));

__device__ __forceinline__ unsigned short f2b(float x) {
    unsigned int b = __float_as_uint(x);
    b = b + 0x7FFFu + ((b >> 16) & 1u);   // round-to-nearest-even
    return (unsigned short)(b >> 16);
}
__device__ __forceinline__ unsigned short f2b_trunc(float x) {
    return (unsigned short)(__float_as_uint(x) >> 16);   // cheap, for P only
}
__device__ __forceinline__ float b2f(unsigned short u) {
    return __uint_as_float(((unsigned int)u) << 16);
}
__device__ __forceinline__ float gelu_f(float x) {
    return 0.5f * x * (1.0f + erff(x * 0.70710678118654752440f));
}
__device__ __forceinline__ float fexp2(float x) {
    return __builtin_amdgcn_exp2f(x);     // raw v_exp_f32; x=-1e30 -> 0
}
__device__ __forceinline__ floatx4 mfma16(bf16x8 a, bf16x8 b, floatx4 c) {
    return __builtin_amdgcn_mfma_f32_16x16x32_bf16(a, b, c, 0, 0, 0);
}
// async global->LDS, 16B per lane; lane i lands at ldsbase + i*16
__device__ __forceinline__ void gl2lds16(const unsigned short* g, unsigned short* l) {
    __builtin_amdgcn_global_load_lds(
        (__attribute__((address_space(1))) void*)g,
        (__attribute__((address_space(3))) void*)l, 16, 0, 0);
}

// inv_freq[i] = 1e6^(-i/16), i = 0..15
__constant__ float INV_FREQ[16] = {
    1.0f, 0.42169650342858224f, 0.17782794100389228f, 0.074989420933245582f,
    0.031622776601683791f, 0.013335214321633240f, 0.0056234132519034908f,
    0.0023713737056616552f, 0.001f, 4.2169650342858224e-4f,
    1.7782794100389228e-4f, 7.4989420933245582e-5f, 3.1622776601683791e-5f,
    1.3335214321633240e-5f, 5.6234132519034908e-6f, 2.3713737056616552e-6f
};

// s-chunk schedule, 128-q-row tiles: nc = qt/4+1 chunks of 512 s (last partial).
// Ordered longest-first: 24 full (8-step) chunks, then 16 finals by length.
__constant__ unsigned char CHUNK_QT[40] = {
    15,15,15, 14,14,14, 13,13,13, 12,12,12, 11,11, 10,10, 9,9, 8,8, 7,6,5,4,
    15,11,7,3, 14,10,6,2, 13,9,5,1, 12,8,4,0};
__constant__ unsigned char CHUNK_C[40] = {
    0,1,2, 0,1,2, 0,1,2, 0,1,2, 0,1, 0,1, 0,1, 0,1, 0,0,0,0,
    3,2,1,0, 3,2,1,0, 3,2,1,0, 3,2,1,0};

// ---------------------------------------------------------------------------
// One-launch fp32->bf16 conversion of three buffers.
// ---------------------------------------------------------------------------
__global__ __launch_bounds__(256) void cvt3_f32_bf16(
    const float* __restrict__ s0, unsigned short* __restrict__ d0, int n0,
    const float* __restrict__ s1, unsigned short* __restrict__ d1, int n1,
    const float* __restrict__ s2, unsigned short* __restrict__ d2, int n2) {
    int i = blockIdx.x * 256 + threadIdx.x;
    const float* s; unsigned short* d;
    if (i < n0)           { s = s0; d = d0; }
    else if (i < n0 + n1) { i -= n0; s = s1; d = d1; }
    else                  { i -= n0 + n1; s = s2; d = d2; if (i >= n2) return; }
    const float4* sp = reinterpret_cast<const float4*>(s) + (size_t)i * 2;
    float4 a = sp[0], b = sp[1];
    ushort8v r;
    r[0] = f2b(a.x); r[1] = f2b(a.y); r[2] = f2b(a.z); r[3] = f2b(a.w);
    r[4] = f2b(b.x); r[5] = f2b(b.y); r[6] = f2b(b.z); r[7] = f2b(b.w);
    *(reinterpret_cast<ushort8v*>(d) + i) = r;
}

// ---------------------------------------------------------------------------
// QKV GEMM, 128x192 tile, BK=64, 256 threads (4 waves as 2M x 2N, wave-tile
// 64x96), 4-phase counted-vmcnt schedule. [R14 geometry: full 512-block grid
// = exactly 2 blocks/CU, LDS 80 KiB, so both fill and inter-block overlap.]
// LDS halves per buffer (ushort offsets): A0 @0 (4096), B0 @4096 (6144),
// A1 @10240 (4096), B1 @14336 (6144). Subtiled layout per half:
// off(r, kq) = (r>>3)*256 + kq*64 + (r&7)*8 ushorts (conflict-free, meas. 0).
// Stage loads: A-half = 2 gl2lds/thread, B-half = 3.
// vmcnt ledger (loads): prologue stages tile0 {A0,B0,A1,B1}=10 + tile1
// {A0,B0,A1}=7 -> vmcnt(7) = tile0 resident.  Per K-tile stages:
//   ph0: B1(kt+1)[3]  ph1: A0(kt+2)[2]  ph2: B0(kt+2)[3]  ph3: A1(kt+2)[2]
// Gate at ph3: vmcnt(7) retires everything through B1(kt+1) = tile kt+1
// fully resident; kt==NT-2 -> vmcnt(0).
// Overwrite liveness: each staged slot's last reads are covered by the
// lgkmcnt(0) >=1 barrier before the stage (hand-checked all 4 pairs).
// Phases: (ks, nt-triple); A frags held across the two nt-triples of a ks.
// ---------------------------------------------------------------------------
__global__ __launch_bounds__(256, 2) void gemm_qkv_p2(
    const unsigned short* __restrict__ A, const unsigned short* __restrict__ B,
    const float* __restrict__ bias, unsigned short* __restrict__ P,
    int M, int N, int K) {
    __shared__ unsigned short Ls[2][20480];   // 2 x 40 KiB
    const int tid = threadIdx.x;
    const int wave = tid >> 6, lane = tid & 63;
    const int row16 = lane & 15, quad = lane >> 4;
    const int wrow = wave >> 1, wcol = wave & 1;     // 2 x 2 wave grid
    const int bm0 = blockIdx.y * 128, bn0 = blockIdx.x * 192;
    const int NT = K >> 6;

    floatx4 acc[4][6] = {};

    // stage one half: hf 0=A-ks0, 1=B-ks0, 2=A-ks1, 3=B-ks1
    auto stage_half = [&](int kt, int hf) {
        const bool isB = hf & 1;
        const unsigned short* mat = isB ? B : A;
        const int rbase = isB ? bn0 : bm0;
        const int colb = kt * 64 + (hf >> 1) * 32;
        const int hoff = ((hf & 1) ? 4096 : 0) + (hf >> 1) * 10240;
        unsigned short* dst = &Ls[kt & 1][hoff];
        const int nrd = isB ? 3 : 2;
        #pragma unroll
        for (int rd = 0; rd < 3; ++rd) {
            if (rd >= nrd) break;
            int g = tid + rd * 256;
            int rl = g & 7, c4 = (g >> 3) & 3, r8 = g >> 5;
            gl2lds16(mat + (size_t)(rbase + r8 * 8 + rl) * K + colb + c4 * 8,
                     dst + g * 8);
        }
    };

    // prologue: tile0 complete + tile1 {A0,B0,A1}; 17 loads out, retire 10
    stage_half(0, 0); stage_half(0, 1); stage_half(0, 2); stage_half(0, 3);
    stage_half(1, 0); stage_half(1, 1); stage_half(1, 2);
    asm volatile("s_waitcnt vmcnt(7)" ::: "memory");   // tile 0 resident
    __builtin_amdgcn_s_barrier();

    // per-thread fragment base offsets (ushorts within a half)
    const int ra = wrow * 64 + row16;
    const int rb = wcol * 96 + row16;
    const int aoff = (ra >> 3) * 256 + quad * 64 + (ra & 7) * 8;
    const int boff = (rb >> 3) * 256 + quad * 64 + (rb & 7) * 8;

    for (int kt = 0; kt < NT; ++kt) {
        const int bsel = kt & 1;
        bf16x8 af[4], bfr[3];
        // ---- phase 0: ks0, nt{0,1,2} ----
        #pragma unroll
        for (int mt = 0; mt < 4; ++mt)
            af[mt] = *reinterpret_cast<const bf16x8*>(&Ls[bsel][aoff + mt * 512]);
        #pragma unroll
        for (int j = 0; j < 3; ++j)
            bfr[j] = *reinterpret_cast<const bf16x8*>(&Ls[bsel][4096 + boff + j * 512]);
        if (kt + 1 < NT) stage_half(kt + 1, 3);
        __builtin_amdgcn_s_barrier();
        asm volatile("s_waitcnt lgkmcnt(0)" ::: "memory");
        __builtin_amdgcn_sched_barrier(0);
        __builtin_amdgcn_s_setprio(1);
        #pragma unroll
        for (int mt = 0; mt < 4; ++mt)
            #pragma unroll
            for (int j = 0; j < 3; ++j)
                acc[mt][j] = mfma16(af[mt], bfr[j], acc[mt][j]);
        __builtin_amdgcn_s_setprio(0);
        __builtin_amdgcn_s_barrier();
        // ---- phase 1: ks0, nt{3,4,5} (af held) ----
        #pragma unroll
        for (int j = 0; j < 3; ++j)
            bfr[j] = *reinterpret_cast<const bf16x8*>(&Ls[bsel][4096 + boff + (3 + j) * 512]);
        if (kt + 2 < NT) stage_half(kt + 2, 0);
        __builtin_amdgcn_s_barrier();
        asm volatile("s_waitcnt lgkmcnt(0)" ::: "memory");
        __builtin_amdgcn_sched_barrier(0);
        __builtin_amdgcn_s_setprio(1);
        #pragma unroll
        for (int mt = 0; mt < 4; ++mt)
            #pragma unroll
            for (int j = 0; j < 3; ++j)
                acc[mt][3 + j] = mfma16(af[mt], bfr[j], acc[mt][3 + j]);
        __builtin_amdgcn_s_setprio(0);
        __builtin_amdgcn_s_barrier();
        // ---- phase 2: ks1, nt{0,1,2} ----
        #pragma unroll
        for (int mt = 0; mt < 4; ++mt)
            af[mt] = *reinterpret_cast<const bf16x8*>(&Ls[bsel][10240 + aoff + mt * 512]);
        #pragma unroll
        for (int j = 0; j < 3; ++j)
            bfr[j] = *reinterpret_cast<const bf16x8*>(&Ls[bsel][14336 + boff + j * 512]);
        if (kt + 2 < NT) stage_half(kt + 2, 1);
        __builtin_amdgcn_s_barrier();
        asm volatile("s_waitcnt lgkmcnt(0)" ::: "memory");
        __builtin_amdgcn_sched_barrier(0);
        __builtin_amdgcn_s_setprio(1);
        #pragma unroll
        for (int mt = 0; mt < 4; ++mt)
            #pragma unroll
            for (int j = 0; j < 3; ++j)
                acc[mt][j] = mfma16(af[mt], bfr[j], acc[mt][j]);
        __builtin_amdgcn_s_setprio(0);
        __builtin_amdgcn_s_barrier();
        // ---- phase 3: ks1, nt{3,4,5} ----
        #pragma unroll
        for (int j = 0; j < 3; ++j)
            bfr[j] = *reinterpret_cast<const bf16x8*>(&Ls[bsel][14336 + boff + (3 + j) * 512]);
        if (kt + 2 < NT) stage_half(kt + 2, 2);
        if (kt == NT - 2)     asm volatile("s_waitcnt vmcnt(0)" ::: "memory");
        else if (kt < NT - 2) asm volatile("s_waitcnt vmcnt(7)" ::: "memory");
        __builtin_amdgcn_s_barrier();
        asm volatile("s_waitcnt lgkmcnt(0)" ::: "memory");
        __builtin_amdgcn_sched_barrier(0);
        __builtin_amdgcn_s_setprio(1);
        #pragma unroll
        for (int mt = 0; mt < 4; ++mt)
            #pragma unroll
            for (int j = 0; j < 3; ++j)
                acc[mt][3 + j] = mfma16(af[mt], bfr[j], acc[mt][3 + j]);
        __builtin_amdgcn_s_setprio(0);
        __builtin_amdgcn_s_barrier();
    }

    // epilogue: bias + bf16 store
    #pragma unroll
    for (int mt = 0; mt < 4; ++mt) {
        #pragma unroll
        for (int nt = 0; nt < 6; ++nt) {
            int gc = bn0 + wcol * 96 + nt * 16 + row16;
            float bv = bias[gc];
            int gr0 = bm0 + wrow * 64 + mt * 16 + quad * 4;
            #pragma unroll
            for (int i = 0; i < 4; ++i)
                P[(size_t)(gr0 + i) * N + gc] = f2b(acc[mt][nt][i] + bv);
        }
    }
}

// ---------------------------------------------------------------------------
// bf16 GEMM: C[M,N] = A[M,K] @ B[N,K]^T + bias[N].  BMxBN tile, BK=64.
// (plain R4 form: R6 A/B showed lgkm/setprio discipline + XCD swizzle are
//  null at 4 blocks/CU -> reverted for clean attribution)
// ---------------------------------------------------------------------------
template <int BM, int BN, bool OUT_BF16>
__global__ __launch_bounds__(256) void gemm_bf16_bt(
    const unsigned short* __restrict__ A, const unsigned short* __restrict__ B,
    const float* __restrict__ bias, void* __restrict__ Cout,
    int M, int N, int K) {
    constexpr int MT = BM / 32, NT = BN / 32;
    __shared__ unsigned short As[BM * 64];
    __shared__ unsigned short Bs[BN * 64];
    const int tid = threadIdx.x;
    const int wave = tid >> 6, lane = tid & 63;
    const int row16 = lane & 15, quad = lane >> 4;
    const int wm = (wave >> 1) * (BM / 2), wn = (wave & 1) * (BN / 2);
    const int bm0 = blockIdx.y * BM, bn0 = blockIdx.x * BN;
    const int rl = lane & 7, cl = lane >> 3;

    floatx4 acc[MT][NT] = {};

    for (int k0 = 0; k0 < K; k0 += 64) {
        __syncthreads();
        #pragma unroll
        for (int j = 0; j < BM / 32; ++j) {
            int unit = wave * (BM / 32) + j;
            const unsigned short* ga = A + (size_t)(bm0 + unit * 8 + rl) * K + k0 + cl * 8;
            gl2lds16(ga, &As[unit * 512 + lane * 8]);
        }
        #pragma unroll
        for (int j = 0; j < BN / 32; ++j) {
            int unit = wave * (BN / 32) + j;
            const unsigned short* gb = B + (size_t)(bn0 + unit * 8 + rl) * K + k0 + cl * 8;
            gl2lds16(gb, &Bs[unit * 512 + lane * 8]);
        }
        __syncthreads();

        #pragma unroll
        for (int ks = 0; ks < 2; ++ks) {
            bf16x8 af[MT], bfr[NT];
            #pragma unroll
            for (int mt = 0; mt < MT; ++mt) {
                int r = wm + mt * 16 + row16;
                af[mt] = *reinterpret_cast<const bf16x8*>(
                    &As[(r >> 3) * 512 + (ks * 4 + quad) * 64 + (r & 7) * 8]);
            }
            #pragma unroll
            for (int nt = 0; nt < NT; ++nt) {
                int r = wn + nt * 16 + row16;
                bfr[nt] = *reinterpret_cast<const bf16x8*>(
                    &Bs[(r >> 3) * 512 + (ks * 4 + quad) * 64 + (r & 7) * 8]);
            }
            #pragma unroll
            for (int mt = 0; mt < MT; ++mt)
                #pragma unroll
                for (int nt = 0; nt < NT; ++nt)
                    acc[mt][nt] = mfma16(af[mt], bfr[nt], acc[mt][nt]);
        }
    }

    #pragma unroll
    for (int mt = 0; mt < MT; ++mt) {
        #pragma unroll
        for (int nt = 0; nt < NT; ++nt) {
            int gc = bn0 + wn + nt * 16 + row16;
            float bv = bias[gc];
            int gr0 = bm0 + wm + mt * 16 + quad * 4;
            #pragma unroll
            for (int i = 0; i < 4; ++i) {
                float v = acc[mt][nt][i] + bv;
                if (OUT_BF16)
                    ((unsigned short*)Cout)[(size_t)(gr0 + i) * N + gc] = f2b(v);
                else
                    ((float*)Cout)[(size_t)(gr0 + i) * N + gc] = v;
            }
        }
    }
}

// ---------------------------------------------------------------------------
// tok GEMM split-K: C[2048,64] += gelu(P) @ [Bq;Bv]^T; C pre-zeroed.
// ---------------------------------------------------------------------------
template <int KSPLIT>
__global__ __launch_bounds__(256) void tok_gemm_splitk(
    const unsigned short* __restrict__ A0,
    const float* __restrict__ Bq, const float* __restrict__ Bv,
    float* __restrict__ C, int K) {
    constexpr int LDT = 72;
    __shared__ unsigned short As[64 * LDT];
    __shared__ unsigned short Bs[64 * LDT];
    const int tid = threadIdx.x;
    const int wave = tid >> 6, lane = tid & 63;
    const int row16 = lane & 15, quad = lane >> 4;
    const int wm = (wave >> 1) * 32, wn = (wave & 1) * 32;
    const int bm0 = blockIdx.y * 64;
    const int kbeg = blockIdx.x * KSPLIT;

    floatx4 acc[2][2] = {};

    for (int k0 = kbeg; k0 < kbeg + KSPLIT; k0 += 64) {
        #pragma unroll
        for (int it = 0; it < 2; ++it) {
            int i = tid + it * 256;
            int r = i >> 3, c8 = i & 7;
            size_t off = (size_t)(bm0 + r) * K + k0 + c8 * 8;
            ushort8v a0 = *reinterpret_cast<const ushort8v*>(A0 + off);
            ushort8v g;
            #pragma unroll
            for (int j = 0; j < 8; ++j) g[j] = f2b(gelu_f(b2f(a0[j])));
            *reinterpret_cast<ushort8v*>(&As[r * LDT + c8 * 8]) = g;

            const float* brow = (r < 32) ? (Bq + (size_t)r * K) : (Bv + (size_t)(r - 32) * K);
            float4 w0 = *reinterpret_cast<const float4*>(brow + k0 + c8 * 8);
            float4 w1 = *reinterpret_cast<const float4*>(brow + k0 + c8 * 8 + 4);
            ushort8v wb;
            wb[0] = f2b(w0.x); wb[1] = f2b(w0.y); wb[2] = f2b(w0.z); wb[3] = f2b(w0.w);
            wb[4] = f2b(w1.x); wb[5] = f2b(w1.y); wb[6] = f2b(w1.z); wb[7] = f2b(w1.w);
            *reinterpret_cast<ushort8v*>(&Bs[r * LDT + c8 * 8]) = wb;
        }
        __syncthreads();

        #pragma unroll
        for (int ks = 0; ks < 2; ++ks) {
            bf16x8 af[2], bfr[2];
            #pragma unroll
            for (int mt = 0; mt < 2; ++mt)
                af[mt] = *reinterpret_cast<const bf16x8*>(
                    &As[(wm + mt * 16 + row16) * LDT + ks * 32 + quad * 8]);
            #pragma unroll
            for (int nt = 0; nt < 2; ++nt)
                bfr[nt] = *reinterpret_cast<const bf16x8*>(
                    &Bs[(wn + nt * 16 + row16) * LDT + ks * 32 + quad * 8]);
            #pragma unroll
            for (int mt = 0; mt < 2; ++mt)
                #pragma unroll
                for (int nt = 0; nt < 2; ++nt)
                    acc[mt][nt] = mfma16(af[mt], bfr[nt], acc[mt][nt]);
        }
        __syncthreads();
    }

    #pragma unroll
    for (int mt = 0; mt < 2; ++mt)
        #pragma unroll
        for (int nt = 0; nt < 2; ++nt) {
            int gc = wn + nt * 16 + row16;
            int gr0 = bm0 + wm + mt * 16 + quad * 4;
            #pragma unroll
            for (int i = 0; i < 4; ++i)
                atomicAdd(&C[(size_t)(gr0 + i) * 64 + gc], acc[mt][nt][i]);
        }
}

// ---------------------------------------------------------------------------
// tau gating + RoPE + layout transforms; qkv = P (bf16, bias included).
// V is packed fragment-ordered: vpk[h][sb32][nt][quad][m][8] where
// element = V[d=nt*16+m][s=sb*32+quad*8+j] -> attn B-frag load is
// base + lane*16B (fully coalesced). q pre-scaled by 0.125*log2e.
// ---------------------------------------------------------------------------
__global__ __launch_bounds__(256) void qkv_process(
    const unsigned short* __restrict__ P,
    const float* __restrict__ tok_raw, const float* __restrict__ tau_alpha,
    const int* __restrict__ positions, unsigned short* __restrict__ qh,
    unsigned short* __restrict__ kh, unsigned short* __restrict__ vpk) {
    const int h = blockIdx.y;
    const int t0 = blockIdx.x * 64;
    const int tid = threadIdx.x;
    __shared__ float vtr[64][65];
    __shared__ float tauq_s[64], tauv_s[64];

    if (tid < 64) {
        int t = t0 + tid;
        float pos = (float)positions[t];
        float pl = logf(fmaxf(pos + 1.0f, 1e-6f));
        float a = tau_alpha[h];
        float tp = 0.5f + 1.0f / (1.0f + __expf(-a * pl));
        tauq_s[tid] = tanhf(tok_raw[t * 64 + h]) + tp;
        tauv_s[tid] = tanhf(tok_raw[t * 64 + 32 + h]) + tp;
    }
    __syncthreads();

    const float QSCALE = 0.18033688011112042f;   // 0.125 * log2(e)
    #pragma unroll
    for (int it = 0; it < 2; ++it) {
        int idx = tid + it * 256;
        int tl = idx >> 3, c8 = idx & 7;
        int t = t0 + tl;
        size_t rb = (size_t)t * 6144 + h * 64 + c8 * 8;
        ushort8v q0v = *reinterpret_cast<const ushort8v*>(P + rb);
        ushort8v k0v = *reinterpret_cast<const ushort8v*>(P + rb + 2048);
        ushort8v v0v = *reinterpret_cast<const ushort8v*>(P + rb + 4096);
        float tq = tauq_s[tl], tv = tauv_s[tl];
        float qo[8], ko[8];
        #pragma unroll
        for (int j = 0; j < 8; ++j) {
            qo[j] = b2f(q0v[j]) * tq;
            ko[j] = b2f(k0v[j]);
        }
        if (c8 < 4) {                          // rotary chunks 0..3
            size_t rp = (size_t)t * 6144 + h * 64 + (c8 ^ 2) * 8;
            ushort8v qp0 = *reinterpret_cast<const ushort8v*>(P + rp);
            ushort8v kp0 = *reinterpret_cast<const ushort8v*>(P + rp + 2048);
            float pos = (float)positions[t];
            float sgn = (c8 < 2) ? -1.0f : 1.0f;
            #pragma unroll
            for (int j = 0; j < 8; ++j) {
                int fi = (c8 * 8 + j) & 15;
                float ang = pos * INV_FREQ[fi];
                float s, c;
                sincosf(ang, &s, &c);
                float qp = b2f(qp0[j]) * tq;
                float kp = b2f(kp0[j]);
                qo[j] = qo[j] * c + sgn * qp * s;
                ko[j] = ko[j] * c + sgn * kp * s;
            }
        }
        size_t ob = ((size_t)h * 2048 + t) * 64 + c8 * 8;
        ushort8v qw, kw;
        #pragma unroll
        for (int j = 0; j < 8; ++j) {
            qw[j] = f2b(qo[j] * QSCALE);
            kw[j] = f2b(ko[j]);
        }
        *reinterpret_cast<ushort8v*>(qh + ob) = qw;
        *reinterpret_cast<ushort8v*>(kh + ob) = kw;
        #pragma unroll
        for (int j = 0; j < 8; ++j)
            vtr[c8 * 8 + j][tl] = b2f(v0v[j]) * tv;
    }
    __syncthreads();
    // V pack: vpk[h][sb32][nt][quad][m][8] = V[d=nt*16+m][s=sb*32+quad*8+j]
    #pragma unroll
    for (int it = 0; it < 2; ++it) {
        int idx = tid + it * 256;
        int d = idx >> 3, tc = (idx & 7) * 8;      // s-chunk [t0+tc, t0+tc+8)
        int sb = (t0 + tc) >> 5;
        int quad = (tc & 31) >> 3;
        int nt = d >> 4, m = d & 15;
        ushort8v w;
        #pragma unroll
        for (int j = 0; j < 8; ++j) w[j] = f2b(vtr[d][tc + j]);
        *reinterpret_cast<ushort8v*>(
            vpk + (size_t)h * 131072 + sb * 2048 + nt * 512 + quad * 128 + m * 8) = w;
    }
}

// ---------------------------------------------------------------------------
// s-split MAX-FREE flash attention, XCD-affine 1D schedule (R9 config).
// b&7 = XCD slot; head = (b&7) + 8*((b>>3)&3) -> 4 heads per XCD. cpos=b>>5
// walks 40 chunks longest-first. Wave owns 32 q-rows (2 m-frags).
// P = 2^s directly (scale folded into qh); masked -> 0.
// V loads from fragment-packed vpk: one coalesced 16B/lane load per frag.
// ---------------------------------------------------------------------------
__global__ __launch_bounds__(256) void attn_fa(
    const unsigned short* __restrict__ qh, const unsigned short* __restrict__ kh,
    const unsigned short* __restrict__ vpk, unsigned short* __restrict__ Opart,
    float* __restrict__ ml) {
    constexpr int LD = 72;
    __shared__ unsigned short pbuf[4][2][16 * LD];   // [wave][mt]
    const int b = blockIdx.x;
    const int h = (b & 7) + 8 * ((b >> 3) & 3);
    const int cpos = b >> 5;
    const int qt = CHUNK_QT[cpos], ch = CHUNK_C[cpos];
    const int q0 = qt * 128;
    const int slot = (h * 16 + qt) * 4 + ch;
    const int wave = threadIdx.x >> 6, lane = threadIdx.x & 63;
    const int m = lane & 15, quad = lane >> 4;
    const int qrow0 = q0 + wave * 32;
    const int sbeg = ch * 512;
    const int send = min(sbeg + 512, qrow0 + 32);

    bf16x8 aq[2][2];
    #pragma unroll
    for (int mt = 0; mt < 2; ++mt) {
        const unsigned short* qptr = qh + ((size_t)h * 2048 + qrow0 + mt * 16 + m) * 64;
        aq[mt][0] = *reinterpret_cast<const bf16x8*>(qptr + quad * 8);
        aq[mt][1] = *reinterpret_cast<const bf16x8*>(qptr + 32 + quad * 8);
    }
    const unsigned short* kbase = kh + (size_t)h * 2048 * 64;
    const unsigned short* vbase = vpk + (size_t)h * 131072;

    floatx4 o[2][4] = {};
    float lsum[2][4] = {};

    for (int s0 = sbeg; s0 < send; s0 += 64) {
        floatx4 sc[2][4];
        #pragma unroll
        for (int sg = 0; sg < 4; ++sg) {
            const unsigned short* kr = kbase + (size_t)(s0 + sg * 16 + m) * 64;
            bf16x8 bk0 = *reinterpret_cast<const bf16x8*>(kr + quad * 8);
            bf16x8 bk1 = *reinterpret_cast<const bf16x8*>(kr + 32 + quad * 8);
            #pragma unroll
            for (int mt = 0; mt < 2; ++mt) {
                floatx4 z = {};
                z = mfma16(aq[mt][0], bk0, z);
                z = mfma16(aq[mt][1], bk1, z);
                sc[mt][sg] = z;
            }
        }
        if (s0 + 63 > qrow0) {               // only near-diagonal steps mask
            #pragma unroll
            for (int mt = 0; mt < 2; ++mt)
                #pragma unroll
                for (int sg = 0; sg < 4; ++sg)
                    #pragma unroll
                    for (int i = 0; i < 4; ++i) {
                        int t = qrow0 + mt * 16 + quad * 4 + i;
                        int s = s0 + sg * 16 + m;
                        sc[mt][sg][i] = (s > t) ? -1e30f : sc[mt][sg][i];
                    }
        }
        // P = 2^s directly (max-free, scale pre-folded); masked -> 0
        #pragma unroll
        for (int mt = 0; mt < 2; ++mt)
            #pragma unroll
            for (int sg = 0; sg < 4; ++sg)
                #pragma unroll
                for (int i = 0; i < 4; ++i)
                    sc[mt][sg][i] = fexp2(sc[mt][sg][i]);
        #pragma unroll
        for (int mt = 0; mt < 2; ++mt)
            #pragma unroll
            for (int i = 0; i < 4; ++i)
                lsum[mt][i] += (sc[mt][0][i] + sc[mt][1][i]) + (sc[mt][2][i] + sc[mt][3][i]);

        // P: C-layout regs -> wave-private LDS -> A-layout frags (no barrier)
        unsigned short* pb0 = pbuf[wave][0];
        unsigned short* pb1 = pbuf[wave][1];
        #pragma unroll
        for (int sg = 0; sg < 4; ++sg)
            #pragma unroll
            for (int i = 0; i < 4; ++i) {
                pb0[(quad * 4 + i) * LD + sg * 16 + m] = f2b_trunc(sc[0][sg][i]);
                pb1[(quad * 4 + i) * LD + sg * 16 + m] = f2b_trunc(sc[1][sg][i]);
            }
        bf16x8 ap[2][2];
        #pragma unroll
        for (int mt = 0; mt < 2; ++mt) {
            ap[mt][0] = *reinterpret_cast<const bf16x8*>(&pbuf[wave][mt][m * LD + quad * 8]);
            ap[mt][1] = *reinterpret_cast<const bf16x8*>(&pbuf[wave][mt][m * LD + 32 + quad * 8]);
        }
        #pragma unroll
        for (int c = 0; c < 2; ++c) {
            const unsigned short* vrow = vbase + ((s0 >> 5) + c) * 2048;
            #pragma unroll
            for (int nt = 0; nt < 4; ++nt) {
                bf16x8 bv = *reinterpret_cast<const bf16x8*>(vrow + nt * 512 + lane * 8);
                o[0][nt] = mfma16(ap[0][c], bv, o[0][nt]);
                o[1][nt] = mfma16(ap[1][c], bv, o[1][nt]);
            }
        }
    }

    // epilogue: reduce l across the 16 column-lanes, store partials
    #pragma unroll
    for (int d = 1; d < 16; d <<= 1)
        #pragma unroll
        for (int mt = 0; mt < 2; ++mt)
            #pragma unroll
            for (int i = 0; i < 4; ++i)
                lsum[mt][i] += __shfl_xor(lsum[mt][i], d, 16);
    #pragma unroll
    for (int mt = 0; mt < 2; ++mt) {
        #pragma unroll
        for (int nt = 0; nt < 4; ++nt)
            #pragma unroll
            for (int i = 0; i < 4; ++i)
                Opart[((size_t)slot * 128 + wave * 32 + mt * 16 + quad * 4 + i) * 64 + nt * 16 + m]
                    = f2b(o[mt][nt][i]);
        if (m == 0) {
            #pragma unroll
            for (int i = 0; i < 4; ++i)
                ml[(size_t)slot * 128 + wave * 32 + mt * 16 + quad * 4 + i] = lsum[mt][i];
        }
    }
}

// ---------------------------------------------------------------------------
// Merge s-split partials (max-free): O = sum_c O~_c / sum_c l_c.
// Block = (qt, h); thread t: row t/2, cols (t&1)*32 .. +32.
// ---------------------------------------------------------------------------
__global__ __launch_bounds__(256) void attn_merge(
    const unsigned short* __restrict__ Opart, const float* __restrict__ ml,
    unsigned short* __restrict__ attnb) {
    const int qt = blockIdx.x, h = blockIdx.y;
    const int nc = qt / 4 + 1;
    const int tid = threadIdx.x;
    const int r = tid >> 1, dh = (tid & 1) * 32;
    const int bs = (h * 16 + qt) * 4;

    float denom = 0.0f;
    #pragma unroll
    for (int c = 0; c < 4; ++c)
        if (c < nc) denom += ml[(size_t)(bs + c) * 128 + r];
    float inv = 1.0f / denom;

    float acc[32] = {};
    #pragma unroll
    for (int c = 0; c < 4; ++c) {
        if (c < nc) {
            const unsigned short* op = Opart + ((size_t)(bs + c) * 128 + r) * 64 + dh;
            #pragma unroll
            for (int j = 0; j < 4; ++j) {
                ushort8v v = *reinterpret_cast<const ushort8v*>(op + j * 8);
                #pragma unroll
                for (int k = 0; k < 8; ++k)
                    acc[j * 8 + k] += b2f(v[k]);
            }
        }
    }
    unsigned short* dst = attnb + (size_t)(qt * 128 + r) * 2048 + h * 64 + dh;
    #pragma unroll
    for (int j = 0; j < 4; ++j) {
        ushort8v v;
        #pragma unroll
        for (int k = 0; k < 8; ++k) v[k] = f2b(acc[j * 8 + k] * inv);
        *reinterpret_cast<ushort8v*>(dst + j * 8) = v;
    }
}

// ---------------------------------------------------------------------------
extern "C" void kernel_launch(void* const* d_in, const int* in_sizes, int n_in,
                              void* d_out, int out_size, void* d_ws, size_t ws_size,
                              hipStream_t stream) {
    const int*   positions = (const int*)d_in[0];
    const float* hidden    = (const float*)d_in[1];
    const float* Wqkv      = (const float*)d_in[2];
    const float* bqkv      = (const float*)d_in[3];
    const float* Wout      = (const float*)d_in[4];
    const float* bout      = (const float*)d_in[5];
    const float* tau_alpha = (const float*)d_in[6];
    const float* tau_wq    = (const float*)d_in[7];
    const float* tau_wv    = (const float*)d_in[8];

    unsigned char* ws = (unsigned char*)d_ws;
    unsigned short* P       = (unsigned short*)(ws);             // 25165824
    unsigned short* Opart   = (unsigned short*)(ws);             // reuses P (33.5MB)
    unsigned short* wqb     = (unsigned short*)(ws + 50331648);  // dead after GEMM1
    unsigned short* qh      = (unsigned short*)(ws + 50331648);
    unsigned short* kh      = (unsigned short*)(ws + 58720256);
    unsigned short* vpk     = (unsigned short*)(ws + 67108864);
    unsigned short* hb      = (unsigned short*)(ws + 75497472);  // dead after GEMM1
    float*          tok_raw = (float*)(ws + 75497472);           // after hb dead
    unsigned short* attnb   = (unsigned short*)(ws + 75497472);  // after tok_raw dead
    float*          ml      = (float*)(ws + 83886080);
    unsigned short* wob     = (unsigned short*)(ws + 85983232);

    // 0) fp32 -> bf16 conversions (one launch, 3 segments)
    cvt3_f32_bf16<<<10240, 256, 0, stream>>>(
        hidden, hb, 524288, Wqkv, wqb, 1572864, Wout, wob, 524288);
    // 1) QKV GEMM 128x192 tile, 512 blocks = 2/CU (full fill + overlap)
    gemm_qkv_p2<<<dim3(32, 16), 256, 0, stream>>>(
        hb, wqb, bqkv, P, 2048, 6144, 2048);
    // 2) tok_raw = gelu(P) @ [tau_wq;tau_wv]^T  (split-K + atomics)
    hipMemsetAsync(tok_raw, 0, (size_t)2048 * 64 * 4, stream);
    tok_gemm_splitk<256><<<dim3(24, 32), 256, 0, stream>>>(
        P, tau_wq, tau_wv, tok_raw, 6144);
    // 3) gating + RoPE + layouts (vectorized; V fragment-packed)
    qkv_process<<<dim3(32, 32), 256, 0, stream>>>(
        P, tok_raw, tau_alpha, positions, qh, kh, vpk);
    // 4) s-split max-free flash attention, XCD-affine (1280 blocks)
    attn_fa<<<1280, 256, 0, stream>>>(qh, kh, vpk, Opart, ml);
    // 5) merge partials -> attnb
    attn_merge<<<dim3(16, 32), 256, 0, stream>>>(Opart, ml, attnb);
    // 6) out = attnb @ wob^T + bout  (64x64 tile -> 1024 blocks, 4/CU)
    gemm_bf16_bt<64, 64, false><<<dim3(32, 32), 256, 0, stream>>>(
        attnb, wob, bout, d_out, 2048, 2048, 2048);
}

// Round 9
// 367.730 us; speedup vs baseline: 1.0387x; 1.0387x over previous
//
#include <hip/hip_runtime.h>
#include <math.h>

// ---------------------------------------------------------------------------
// Moondream3Attention on MI355X (gfx950)
// T=2048, DIM=2048, H=32, HD=64, ROT=32, QKV_DIM=6144
// Pipeline (all-bf16 matmul datapath):  [R16: full-grid 256x192 QKV GEMM]
//   0) cvt3: hidden->hb, Wqkv->wqb, Wout->wob (fp32->bf16, one launch)
//   1) qkv GEMM: 256x192 tile, BK=64, 512 thr (2x4 waves, 128x48/wave),
//      R4's verified 8-phase/counted-vmcnt/lgkm-discipline structure at a
//      grid of 32x8 = EXACTLY 256 blocks = 1/CU full fill (R4's 24x8=192
//      left 25% of CUs idle; R14 showed occupancy-via-small-tile loses to
//      barrier amortization, so keep big tile + fix fill instead).
//      Per-wave vmcnt constants (B-half staged non-uniformly: w0-3 2 loads,
//      w4-7 1 load): prologue/steady gate w0-3=vmcnt(6), w4-7=vmcnt(5).
//   2) tok = gelu(P) @ [tau_wq;tau_wv]^T   (split-K + atomics)
//   3) qkv_process (ushort8-vectorized): tau gating + RoPE;
//      V packed fragment-ordered: vpk[h][sb32][nt][quad][m][8]
//   4) attn_fa: s-split MAX-FREE flash attention, 1280 blocks
//   5) attn_merge: O = sum_c O~_c / sum_c l_c -> attnb bf16
//   6) out = attnb @ wob^T + bout (64x64 tile, 1024 blocks, plain R4 form)
// Workspace (94,371,840 B), liveness-overlapped (unchanged from R10).
// ---------------------------------------------------------------------------

typedef __bf16 bf16x8 __attribute__((ext_vector_type(8)));
typedef float floatx4 __attribute__((ext_vector_type(4)));
typedef unsigned short ushort8v __attribute__((ext_vector_type(8)));

__device__ __forceinline__ unsigned short f2b(float x) {
    unsigned int b = __float_as_uint(x);
    b = b + 0x7FFFu + ((b >> 16) & 1u);   // round-to-nearest-even
    return (unsigned short)(b >> 16);
}
__device__ __forceinline__ unsigned short f2b_trunc(float x) {
    return (unsigned short)(__float_as_uint(x) >> 16);   // cheap, for P only
}
__device__ __forceinline__ float b2f(unsigned short u) {
    return __uint_as_float(((unsigned int)u) << 16);
}
__device__ __forceinline__ float gelu_f(float x) {
    return 0.5f * x * (1.0f + erff(x * 0.70710678118654752440f));
}
__device__ __forceinline__ float fexp2(float x) {
    return __builtin_amdgcn_exp2f(x);     // raw v_exp_f32; x=-1e30 -> 0
}
__device__ __forceinline__ floatx4 mfma16(bf16x8 a, bf16x8 b, floatx4 c) {
    return __builtin_amdgcn_mfma_f32_16x16x32_bf16(a, b, c, 0, 0, 0);
}
// async global->LDS, 16B per lane; lane i lands at ldsbase + i*16
__device__ __forceinline__ void gl2lds16(const unsigned short* g, unsigned short* l) {
    __builtin_amdgcn_global_load_lds(
        (__attribute__((address_space(1))) void*)g,
        (__attribute__((address_space(3))) void*)l, 16, 0, 0);
}

// inv_freq[i] = 1e6^(-i/16), i = 0..15
__constant__ float INV_FREQ[16] = {
    1.0f, 0.42169650342858224f, 0.17782794100389228f, 0.074989420933245582f,
    0.031622776601683791f, 0.013335214321633240f, 0.0056234132519034908f,
    0.0023713737056616552f, 0.001f, 4.2169650342858224e-4f,
    1.7782794100389228e-4f, 7.4989420933245582e-5f, 3.1622776601683791e-5f,
    1.3335214321633240e-5f, 5.6234132519034908e-6f, 2.3713737056616552e-6f
};

// s-chunk schedule, 128-q-row tiles: nc = qt/4+1 chunks of 512 s (last partial).
// Ordered longest-first: 24 full (8-step) chunks, then 16 finals by length.
__constant__ unsigned char CHUNK_QT[40] = {
    15,15,15, 14,14,14, 13,13,13, 12,12,12, 11,11, 10,10, 9,9, 8,8, 7,6,5,4,
    15,11,7,3, 14,10,6,2, 13,9,5,1, 12,8,4,0};
__constant__ unsigned char CHUNK_C[40] = {
    0,1,2, 0,1,2, 0,1,2, 0,1,2, 0,1, 0,1, 0,1, 0,1, 0,0,0,0,
    3,2,1,0, 3,2,1,0, 3,2,1,0, 3,2,1,0};

// ---------------------------------------------------------------------------
// One-launch fp32->bf16 conversion of three buffers.
// ---------------------------------------------------------------------------
__global__ __launch_bounds__(256) void cvt3_f32_bf16(
    const float* __restrict__ s0, unsigned short* __restrict__ d0, int n0,
    const float* __restrict__ s1, unsigned short* __restrict__ d1, int n1,
    const float* __restrict__ s2, unsigned short* __restrict__ d2, int n2) {
    int i = blockIdx.x * 256 + threadIdx.x;
    const float* s; unsigned short* d;
    if (i < n0)           { s = s0; d = d0; }
    else if (i < n0 + n1) { i -= n0; s = s1; d = d1; }
    else                  { i -= n0 + n1; s = s2; d = d2; if (i >= n2) return; }
    const float4* sp = reinterpret_cast<const float4*>(s) + (size_t)i * 2;
    float4 a = sp[0], b = sp[1];
    ushort8v r;
    r[0] = f2b(a.x); r[1] = f2b(a.y); r[2] = f2b(a.z); r[3] = f2b(a.w);
    r[4] = f2b(b.x); r[5] = f2b(b.y); r[6] = f2b(b.z); r[7] = f2b(b.w);
    *(reinterpret_cast<ushort8v*>(d) + i) = r;
}

// ---------------------------------------------------------------------------
// QKV GEMM, 256x192 tile, BK=64, 512 threads (8 waves as 2M x 4N, wave-tile
// 128x48 -> acc[8][3]).  Grid 32x8 = 256 blocks = exactly 1/CU (full fill).
// LDS per buffer (ushort offs): A0 @0 (8192), B0 @8192 (6144), A1 @14336
// (8192), B1 @22528 (6144); 2 buffers = 114688 B.  Subtiled layout per half:
// off(r, c4) = (r>>3)*256 + c4*64 + (r&7)*8 ushorts (conflict-free, meas 0).
// Staging: A-half (16KB) = 2 gl2lds/thread; B-half (12KB) = waves 0-3: 2,
// waves 4-7: 1 (granule g=512+tid for tid<256) -> PER-WAVE vmcnt constants.
// Phases (read-heavy alternating with read-free; af[8] held across a ks):
//   ph0: read A0[8]+B0[3]; stage B1(kt+1)[other buf]; MFMA mt0-3 ks0
//   ph1: (no reads)        stage A0(kt+2)[A0 read done ph0]; MFMA mt4-7 ks0
//   ph2: read A1[8]+B1[3]; stage B0(kt+2)[read done ph0];    MFMA mt0-3 ks1
//   ph3: (no reads)        stage A1(kt+2)[read done ph2]; GATE; MFMA mt4-7
// vmcnt ledger (per wave; A=2, B=2/1 loads): prologue t0+{t1 A0,B0,A1} =
// 14/11 out -> retire t0 (8/6) -> vmcnt(6)/(5).  Steady: enter kt with 6/5,
// ph0..ph3 stages add 8/6 -> 14/11; gate after ph3's stage retires tile
// kt+1 (8/6) -> vmcnt(6)/(5); kt==NT-2 -> vmcnt(0).  Gate precedes ph3's
// end barrier -> tile kt+1 visible to all waves before next ph0 reads.
// Overwrite liveness: every stage target's last reads are lgkm(0)-covered
// >=1 barrier before the stage (all 4 pairs hand-checked).
// ---------------------------------------------------------------------------
__global__ __launch_bounds__(512, 1) void gemm_qkv_fg(
    const unsigned short* __restrict__ A, const unsigned short* __restrict__ B,
    const float* __restrict__ bias, unsigned short* __restrict__ P,
    int M, int N, int K) {
    __shared__ unsigned short Ls[2][28672];   // 2 x 56 KiB
    const int tid = threadIdx.x;
    const int wave = tid >> 6, lane = tid & 63;
    const int row16 = lane & 15, quad = lane >> 4;
    const int wrow = wave >> 2, wcol = wave & 3;     // 2 x 4 wave grid
    const int bm0 = blockIdx.y * 256, bn0 = blockIdx.x * 192;
    const int NT = K >> 6;

    floatx4 acc[8][3] = {};

    // stage one half: hf 0=A-ks0, 1=B-ks0, 2=A-ks1, 3=B-ks1
    auto stage_half = [&](int kt, int hf) {
        const bool isB = hf & 1;
        const unsigned short* mat = isB ? B : A;
        const int rbase = isB ? bn0 : bm0;
        const int colb = kt * 64 + (hf >> 1) * 32;
        unsigned short* dst = &Ls[kt & 1][(hf >> 1) * 14336 + (isB ? 8192 : 0)];
        if (isB) {
            {
                int g = tid;
                int rl = g & 7, c4 = (g >> 3) & 3, r8 = g >> 5;
                gl2lds16(mat + (size_t)(rbase + r8 * 8 + rl) * K + colb + c4 * 8,
                         dst + g * 8);
            }
            if (tid < 256) {                       // waves 0-3 only (uniform)
                int g = 512 + tid;
                int rl = g & 7, c4 = (g >> 3) & 3, r8 = g >> 5;
                gl2lds16(mat + (size_t)(rbase + r8 * 8 + rl) * K + colb + c4 * 8,
                         dst + g * 8);
            }
        } else {
            #pragma unroll
            for (int rd = 0; rd < 2; ++rd) {
                int g = tid + rd * 512;
                int rl = g & 7, c4 = (g >> 3) & 3, r8 = g >> 5;
                gl2lds16(mat + (size_t)(rbase + r8 * 8 + rl) * K + colb + c4 * 8,
                         dst + g * 8);
            }
        }
    };

    // prologue: tile0 {A0,B0,A1,B1} + tile1 {A0,B0,A1}; retire tile0
    stage_half(0, 0); stage_half(0, 1); stage_half(0, 2); stage_half(0, 3);
    stage_half(1, 0); stage_half(1, 1); stage_half(1, 2);
    if (wave < 4) asm volatile("s_waitcnt vmcnt(6)" ::: "memory");
    else          asm volatile("s_waitcnt vmcnt(5)" ::: "memory");
    __builtin_amdgcn_s_barrier();

    // per-thread fragment base offsets (ushorts within a half)
    const int ra = wrow * 128 + row16;
    const int rb = wcol * 48 + row16;
    const int aoff = (ra >> 3) * 256 + quad * 64 + (ra & 7) * 8;
    const int boff = (rb >> 3) * 256 + quad * 64 + (rb & 7) * 8;

    for (int kt = 0; kt < NT; ++kt) {
        const int bsel = kt & 1;
        bf16x8 af[8], bfr[3];
        // ---- phase 0: read A0[8]+B0[3]; stage B1(kt+1); MFMA mt0-3 ks0 ----
        #pragma unroll
        for (int mt = 0; mt < 8; ++mt)
            af[mt] = *reinterpret_cast<const bf16x8*>(&Ls[bsel][aoff + mt * 512]);
        #pragma unroll
        for (int j = 0; j < 3; ++j)
            bfr[j] = *reinterpret_cast<const bf16x8*>(&Ls[bsel][8192 + boff + j * 512]);
        if (kt + 1 < NT) stage_half(kt + 1, 3);
        __builtin_amdgcn_s_barrier();
        asm volatile("s_waitcnt lgkmcnt(0)" ::: "memory");
        __builtin_amdgcn_sched_barrier(0);
        __builtin_amdgcn_s_setprio(1);
        #pragma unroll
        for (int mt = 0; mt < 4; ++mt)
            #pragma unroll
            for (int j = 0; j < 3; ++j)
                acc[mt][j] = mfma16(af[mt], bfr[j], acc[mt][j]);
        __builtin_amdgcn_s_setprio(0);
        __builtin_amdgcn_s_barrier();
        // ---- phase 1: stage A0(kt+2); MFMA mt4-7 ks0 (af hi held) ----
        if (kt + 2 < NT) stage_half(kt + 2, 0);
        __builtin_amdgcn_sched_barrier(0);
        __builtin_amdgcn_s_setprio(1);
        #pragma unroll
        for (int mt = 0; mt < 4; ++mt)
            #pragma unroll
            for (int j = 0; j < 3; ++j)
                acc[4 + mt][j] = mfma16(af[4 + mt], bfr[j], acc[4 + mt][j]);
        __builtin_amdgcn_s_setprio(0);
        __builtin_amdgcn_s_barrier();
        // ---- phase 2: read A1[8]+B1[3]; stage B0(kt+2); MFMA mt0-3 ks1 ----
        #pragma unroll
        for (int mt = 0; mt < 8; ++mt)
            af[mt] = *reinterpret_cast<const bf16x8*>(&Ls[bsel][14336 + aoff + mt * 512]);
        #pragma unroll
        for (int j = 0; j < 3; ++j)
            bfr[j] = *reinterpret_cast<const bf16x8*>(&Ls[bsel][22528 + boff + j * 512]);
        if (kt + 2 < NT) stage_half(kt + 2, 1);
        __builtin_amdgcn_s_barrier();
        asm volatile("s_waitcnt lgkmcnt(0)" ::: "memory");
        __builtin_amdgcn_sched_barrier(0);
        __builtin_amdgcn_s_setprio(1);
        #pragma unroll
        for (int mt = 0; mt < 4; ++mt)
            #pragma unroll
            for (int j = 0; j < 3; ++j)
                acc[mt][j] = mfma16(af[mt], bfr[j], acc[mt][j]);
        __builtin_amdgcn_s_setprio(0);
        __builtin_amdgcn_s_barrier();
        // ---- phase 3: stage A1(kt+2); GATE; MFMA mt4-7 ks1 ----
        if (kt + 2 < NT) stage_half(kt + 2, 2);
        if (kt == NT - 2) {
            asm volatile("s_waitcnt vmcnt(0)" ::: "memory");
        } else if (kt < NT - 2) {
            if (wave < 4) asm volatile("s_waitcnt vmcnt(6)" ::: "memory");
            else          asm volatile("s_waitcnt vmcnt(5)" ::: "memory");
        }
        __builtin_amdgcn_sched_barrier(0);
        __builtin_amdgcn_s_setprio(1);
        #pragma unroll
        for (int mt = 0; mt < 4; ++mt)
            #pragma unroll
            for (int j = 0; j < 3; ++j)
                acc[4 + mt][j] = mfma16(af[4 + mt], bfr[j], acc[4 + mt][j]);
        __builtin_amdgcn_s_setprio(0);
        __builtin_amdgcn_s_barrier();
    }

    // epilogue: bias + bf16 store
    #pragma unroll
    for (int mt = 0; mt < 8; ++mt) {
        #pragma unroll
        for (int nt = 0; nt < 3; ++nt) {
            int gc = bn0 + wcol * 48 + nt * 16 + row16;
            float bv = bias[gc];
            int gr0 = bm0 + wrow * 128 + mt * 16 + quad * 4;
            #pragma unroll
            for (int i = 0; i < 4; ++i)
                P[(size_t)(gr0 + i) * N + gc] = f2b(acc[mt][nt][i] + bv);
        }
    }
}

// ---------------------------------------------------------------------------
// bf16 GEMM: C[M,N] = A[M,K] @ B[N,K]^T + bias[N].  BMxBN tile, BK=64.
// ---------------------------------------------------------------------------
template <int BM, int BN, bool OUT_BF16>
__global__ __launch_bounds__(256) void gemm_bf16_bt(
    const unsigned short* __restrict__ A, const unsigned short* __restrict__ B,
    const float* __restrict__ bias, void* __restrict__ Cout,
    int M, int N, int K) {
    constexpr int MT = BM / 32, NT = BN / 32;
    __shared__ unsigned short As[BM * 64];
    __shared__ unsigned short Bs[BN * 64];
    const int tid = threadIdx.x;
    const int wave = tid >> 6, lane = tid & 63;
    const int row16 = lane & 15, quad = lane >> 4;
    const int wm = (wave >> 1) * (BM / 2), wn = (wave & 1) * (BN / 2);
    const int bm0 = blockIdx.y * BM, bn0 = blockIdx.x * BN;
    const int rl = lane & 7, cl = lane >> 3;

    floatx4 acc[MT][NT] = {};

    for (int k0 = 0; k0 < K; k0 += 64) {
        __syncthreads();
        #pragma unroll
        for (int j = 0; j < BM / 32; ++j) {
            int unit = wave * (BM / 32) + j;
            const unsigned short* ga = A + (size_t)(bm0 + unit * 8 + rl) * K + k0 + cl * 8;
            gl2lds16(ga, &As[unit * 512 + lane * 8]);
        }
        #pragma unroll
        for (int j = 0; j < BN / 32; ++j) {
            int unit = wave * (BN / 32) + j;
            const unsigned short* gb = B + (size_t)(bn0 + unit * 8 + rl) * K + k0 + cl * 8;
            gl2lds16(gb, &Bs[unit * 512 + lane * 8]);
        }
        __syncthreads();

        #pragma unroll
        for (int ks = 0; ks < 2; ++ks) {
            bf16x8 af[MT], bfr[NT];
            #pragma unroll
            for (int mt = 0; mt < MT; ++mt) {
                int r = wm + mt * 16 + row16;
                af[mt] = *reinterpret_cast<const bf16x8*>(
                    &As[(r >> 3) * 512 + (ks * 4 + quad) * 64 + (r & 7) * 8]);
            }
            #pragma unroll
            for (int nt = 0; nt < NT; ++nt) {
                int r = wn + nt * 16 + row16;
                bfr[nt] = *reinterpret_cast<const bf16x8*>(
                    &Bs[(r >> 3) * 512 + (ks * 4 + quad) * 64 + (r & 7) * 8]);
            }
            #pragma unroll
            for (int mt = 0; mt < MT; ++mt)
                #pragma unroll
                for (int nt = 0; nt < NT; ++nt)
                    acc[mt][nt] = mfma16(af[mt], bfr[nt], acc[mt][nt]);
        }
    }

    #pragma unroll
    for (int mt = 0; mt < MT; ++mt) {
        #pragma unroll
        for (int nt = 0; nt < NT; ++nt) {
            int gc = bn0 + wn + nt * 16 + row16;
            float bv = bias[gc];
            int gr0 = bm0 + wm + mt * 16 + quad * 4;
            #pragma unroll
            for (int i = 0; i < 4; ++i) {
                float v = acc[mt][nt][i] + bv;
                if (OUT_BF16)
                    ((unsigned short*)Cout)[(size_t)(gr0 + i) * N + gc] = f2b(v);
                else
                    ((float*)Cout)[(size_t)(gr0 + i) * N + gc] = v;
            }
        }
    }
}

// ---------------------------------------------------------------------------
// tok GEMM split-K: C[2048,64] += gelu(P) @ [Bq;Bv]^T; C pre-zeroed.
// ---------------------------------------------------------------------------
template <int KSPLIT>
__global__ __launch_bounds__(256) void tok_gemm_splitk(
    const unsigned short* __restrict__ A0,
    const float* __restrict__ Bq, const float* __restrict__ Bv,
    float* __restrict__ C, int K) {
    constexpr int LDT = 72;
    __shared__ unsigned short As[64 * LDT];
    __shared__ unsigned short Bs[64 * LDT];
    const int tid = threadIdx.x;
    const int wave = tid >> 6, lane = tid & 63;
    const int row16 = lane & 15, quad = lane >> 4;
    const int wm = (wave >> 1) * 32, wn = (wave & 1) * 32;
    const int bm0 = blockIdx.y * 64;
    const int kbeg = blockIdx.x * KSPLIT;

    floatx4 acc[2][2] = {};

    for (int k0 = kbeg; k0 < kbeg + KSPLIT; k0 += 64) {
        #pragma unroll
        for (int it = 0; it < 2; ++it) {
            int i = tid + it * 256;
            int r = i >> 3, c8 = i & 7;
            size_t off = (size_t)(bm0 + r) * K + k0 + c8 * 8;
            ushort8v a0 = *reinterpret_cast<const ushort8v*>(A0 + off);
            ushort8v g;
            #pragma unroll
            for (int j = 0; j < 8; ++j) g[j] = f2b(gelu_f(b2f(a0[j])));
            *reinterpret_cast<ushort8v*>(&As[r * LDT + c8 * 8]) = g;

            const float* brow = (r < 32) ? (Bq + (size_t)r * K) : (Bv + (size_t)(r - 32) * K);
            float4 w0 = *reinterpret_cast<const float4*>(brow + k0 + c8 * 8);
            float4 w1 = *reinterpret_cast<const float4*>(brow + k0 + c8 * 8 + 4);
            ushort8v wb;
            wb[0] = f2b(w0.x); wb[1] = f2b(w0.y); wb[2] = f2b(w0.z); wb[3] = f2b(w0.w);
            wb[4] = f2b(w1.x); wb[5] = f2b(w1.y); wb[6] = f2b(w1.z); wb[7] = f2b(w1.w);
            *reinterpret_cast<ushort8v*>(&Bs[r * LDT + c8 * 8]) = wb;
        }
        __syncthreads();

        #pragma unroll
        for (int ks = 0; ks < 2; ++ks) {
            bf16x8 af[2], bfr[2];
            #pragma unroll
            for (int mt = 0; mt < 2; ++mt)
                af[mt] = *reinterpret_cast<const bf16x8*>(
                    &As[(wm + mt * 16 + row16) * LDT + ks * 32 + quad * 8]);
            #pragma unroll
            for (int nt = 0; nt < 2; ++nt)
                bfr[nt] = *reinterpret_cast<const bf16x8*>(
                    &Bs[(wn + nt * 16 + row16) * LDT + ks * 32 + quad * 8]);
            #pragma unroll
            for (int mt = 0; mt < 2; ++mt)
                #pragma unroll
                for (int nt = 0; nt < 2; ++nt)
                    acc[mt][nt] = mfma16(af[mt], bfr[nt], acc[mt][nt]);
        }
        __syncthreads();
    }

    #pragma unroll
    for (int mt = 0; mt < 2; ++mt)
        #pragma unroll
        for (int nt = 0; nt < 2; ++nt) {
            int gc = wn + nt * 16 + row16;
            int gr0 = bm0 + wm + mt * 16 + quad * 4;
            #pragma unroll
            for (int i = 0; i < 4; ++i)
                atomicAdd(&C[(size_t)(gr0 + i) * 64 + gc], acc[mt][nt][i]);
        }
}

// ---------------------------------------------------------------------------
// tau gating + RoPE + layout transforms; qkv = P (bf16, bias included).
// V is packed fragment-ordered: vpk[h][sb32][nt][quad][m][8] where
// element = V[d=nt*16+m][s=sb*32+quad*8+j] -> attn B-frag load is
// base + lane*16B (fully coalesced). q pre-scaled by 0.125*log2e.
// ---------------------------------------------------------------------------
__global__ __launch_bounds__(256) void qkv_process(
    const unsigned short* __restrict__ P,
    const float* __restrict__ tok_raw, const float* __restrict__ tau_alpha,
    const int* __restrict__ positions, unsigned short* __restrict__ qh,
    unsigned short* __restrict__ kh, unsigned short* __restrict__ vpk) {
    const int h = blockIdx.y;
    const int t0 = blockIdx.x * 64;
    const int tid = threadIdx.x;
    __shared__ float vtr[64][65];
    __shared__ float tauq_s[64], tauv_s[64];

    if (tid < 64) {
        int t = t0 + tid;
        float pos = (float)positions[t];
        float pl = logf(fmaxf(pos + 1.0f, 1e-6f));
        float a = tau_alpha[h];
        float tp = 0.5f + 1.0f / (1.0f + __expf(-a * pl));
        tauq_s[tid] = tanhf(tok_raw[t * 64 + h]) + tp;
        tauv_s[tid] = tanhf(tok_raw[t * 64 + 32 + h]) + tp;
    }
    __syncthreads();

    const float QSCALE = 0.18033688011112042f;   // 0.125 * log2(e)
    #pragma unroll
    for (int it = 0; it < 2; ++it) {
        int idx = tid + it * 256;
        int tl = idx >> 3, c8 = idx & 7;
        int t = t0 + tl;
        size_t rb = (size_t)t * 6144 + h * 64 + c8 * 8;
        ushort8v q0v = *reinterpret_cast<const ushort8v*>(P + rb);
        ushort8v k0v = *reinterpret_cast<const ushort8v*>(P + rb + 2048);
        ushort8v v0v = *reinterpret_cast<const ushort8v*>(P + rb + 4096);
        float tq = tauq_s[tl], tv = tauv_s[tl];
        float qo[8], ko[8];
        #pragma unroll
        for (int j = 0; j < 8; ++j) {
            qo[j] = b2f(q0v[j]) * tq;
            ko[j] = b2f(k0v[j]);
        }
        if (c8 < 4) {                          // rotary chunks 0..3
            size_t rp = (size_t)t * 6144 + h * 64 + (c8 ^ 2) * 8;
            ushort8v qp0 = *reinterpret_cast<const ushort8v*>(P + rp);
            ushort8v kp0 = *reinterpret_cast<const ushort8v*>(P + rp + 2048);
            float pos = (float)positions[t];
            float sgn = (c8 < 2) ? -1.0f : 1.0f;
            #pragma unroll
            for (int j = 0; j < 8; ++j) {
                int fi = (c8 * 8 + j) & 15;
                float ang = pos * INV_FREQ[fi];
                float s, c;
                sincosf(ang, &s, &c);
                float qp = b2f(qp0[j]) * tq;
                float kp = b2f(kp0[j]);
                qo[j] = qo[j] * c + sgn * qp * s;
                ko[j] = ko[j] * c + sgn * kp * s;
            }
        }
        size_t ob = ((size_t)h * 2048 + t) * 64 + c8 * 8;
        ushort8v qw, kw;
        #pragma unroll
        for (int j = 0; j < 8; ++j) {
            qw[j] = f2b(qo[j] * QSCALE);
            kw[j] = f2b(ko[j]);
        }
        *reinterpret_cast<ushort8v*>(qh + ob) = qw;
        *reinterpret_cast<ushort8v*>(kh + ob) = kw;
        #pragma unroll
        for (int j = 0; j < 8; ++j)
            vtr[c8 * 8 + j][tl] = b2f(v0v[j]) * tv;
    }
    __syncthreads();
    // V pack: vpk[h][sb32][nt][quad][m][8] = V[d=nt*16+m][s=sb*32+quad*8+j]
    #pragma unroll
    for (int it = 0; it < 2; ++it) {
        int idx = tid + it * 256;
        int d = idx >> 3, tc = (idx & 7) * 8;      // s-chunk [t0+tc, t0+tc+8)
        int sb = (t0 + tc) >> 5;
        int quad = (tc & 31) >> 3;
        int nt = d >> 4, m = d & 15;
        ushort8v w;
        #pragma unroll
        for (int j = 0; j < 8; ++j) w[j] = f2b(vtr[d][tc + j]);
        *reinterpret_cast<ushort8v*>(
            vpk + (size_t)h * 131072 + sb * 2048 + nt * 512 + quad * 128 + m * 8) = w;
    }
}

// ---------------------------------------------------------------------------
// s-split MAX-FREE flash attention, XCD-affine 1D schedule (R9 config).
// b&7 = XCD slot; head = (b&7) + 8*((b>>3)&3) -> 4 heads per XCD. cpos=b>>5
// walks 40 chunks longest-first. Wave owns 32 q-rows (2 m-frags).
// P = 2^s directly (scale folded into qh); masked -> 0.
// V loads from fragment-packed vpk: one coalesced 16B/lane load per frag.
// ---------------------------------------------------------------------------
__global__ __launch_bounds__(256) void attn_fa(
    const unsigned short* __restrict__ qh, const unsigned short* __restrict__ kh,
    const unsigned short* __restrict__ vpk, unsigned short* __restrict__ Opart,
    float* __restrict__ ml) {
    constexpr int LD = 72;
    __shared__ unsigned short pbuf[4][2][16 * LD];   // [wave][mt]
    const int b = blockIdx.x;
    const int h = (b & 7) + 8 * ((b >> 3) & 3);
    const int cpos = b >> 5;
    const int qt = CHUNK_QT[cpos], ch = CHUNK_C[cpos];
    const int q0 = qt * 128;
    const int slot = (h * 16 + qt) * 4 + ch;
    const int wave = threadIdx.x >> 6, lane = threadIdx.x & 63;
    const int m = lane & 15, quad = lane >> 4;
    const int qrow0 = q0 + wave * 32;
    const int sbeg = ch * 512;
    const int send = min(sbeg + 512, qrow0 + 32);

    bf16x8 aq[2][2];
    #pragma unroll
    for (int mt = 0; mt < 2; ++mt) {
        const unsigned short* qptr = qh + ((size_t)h * 2048 + qrow0 + mt * 16 + m) * 64;
        aq[mt][0] = *reinterpret_cast<const bf16x8*>(qptr + quad * 8);
        aq[mt][1] = *reinterpret_cast<const bf16x8*>(qptr + 32 + quad * 8);
    }
    const unsigned short* kbase = kh + (size_t)h * 2048 * 64;
    const unsigned short* vbase = vpk + (size_t)h * 131072;

    floatx4 o[2][4] = {};
    float lsum[2][4] = {};

    for (int s0 = sbeg; s0 < send; s0 += 64) {
        floatx4 sc[2][4];
        #pragma unroll
        for (int sg = 0; sg < 4; ++sg) {
            const unsigned short* kr = kbase + (size_t)(s0 + sg * 16 + m) * 64;
            bf16x8 bk0 = *reinterpret_cast<const bf16x8*>(kr + quad * 8);
            bf16x8 bk1 = *reinterpret_cast<const bf16x8*>(kr + 32 + quad * 8);
            #pragma unroll
            for (int mt = 0; mt < 2; ++mt) {
                floatx4 z = {};
                z = mfma16(aq[mt][0], bk0, z);
                z = mfma16(aq[mt][1], bk1, z);
                sc[mt][sg] = z;
            }
        }
        if (s0 + 63 > qrow0) {               // only near-diagonal steps mask
            #pragma unroll
            for (int mt = 0; mt < 2; ++mt)
                #pragma unroll
                for (int sg = 0; sg < 4; ++sg)
                    #pragma unroll
                    for (int i = 0; i < 4; ++i) {
                        int t = qrow0 + mt * 16 + quad * 4 + i;
                        int s = s0 + sg * 16 + m;
                        sc[mt][sg][i] = (s > t) ? -1e30f : sc[mt][sg][i];
                    }
        }
        // P = 2^s directly (max-free, scale pre-folded); masked -> 0
        #pragma unroll
        for (int mt = 0; mt < 2; ++mt)
            #pragma unroll
            for (int sg = 0; sg < 4; ++sg)
                #pragma unroll
                for (int i = 0; i < 4; ++i)
                    sc[mt][sg][i] = fexp2(sc[mt][sg][i]);
        #pragma unroll
        for (int mt = 0; mt < 2; ++mt)
            #pragma unroll
            for (int i = 0; i < 4; ++i)
                lsum[mt][i] += (sc[mt][0][i] + sc[mt][1][i]) + (sc[mt][2][i] + sc[mt][3][i]);

        // P: C-layout regs -> wave-private LDS -> A-layout frags (no barrier)
        unsigned short* pb0 = pbuf[wave][0];
        unsigned short* pb1 = pbuf[wave][1];
        #pragma unroll
        for (int sg = 0; sg < 4; ++sg)
            #pragma unroll
            for (int i = 0; i < 4; ++i) {
                pb0[(quad * 4 + i) * LD + sg * 16 + m] = f2b_trunc(sc[0][sg][i]);
                pb1[(quad * 4 + i) * LD + sg * 16 + m] = f2b_trunc(sc[1][sg][i]);
            }
        bf16x8 ap[2][2];
        #pragma unroll
        for (int mt = 0; mt < 2; ++mt) {
            ap[mt][0] = *reinterpret_cast<const bf16x8*>(&pbuf[wave][mt][m * LD + quad * 8]);
            ap[mt][1] = *reinterpret_cast<const bf16x8*>(&pbuf[wave][mt][m * LD + 32 + quad * 8]);
        }
        #pragma unroll
        for (int c = 0; c < 2; ++c) {
            const unsigned short* vrow = vbase + ((s0 >> 5) + c) * 2048;
            #pragma unroll
            for (int nt = 0; nt < 4; ++nt) {
                bf16x8 bv = *reinterpret_cast<const bf16x8*>(vrow + nt * 512 + lane * 8);
                o[0][nt] = mfma16(ap[0][c], bv, o[0][nt]);
                o[1][nt] = mfma16(ap[1][c], bv, o[1][nt]);
            }
        }
    }

    // epilogue: reduce l across the 16 column-lanes, store partials
    #pragma unroll
    for (int d = 1; d < 16; d <<= 1)
        #pragma unroll
        for (int mt = 0; mt < 2; ++mt)
            #pragma unroll
            for (int i = 0; i < 4; ++i)
                lsum[mt][i] += __shfl_xor(lsum[mt][i], d, 16);
    #pragma unroll
    for (int mt = 0; mt < 2; ++mt) {
        #pragma unroll
        for (int nt = 0; nt < 4; ++nt)
            #pragma unroll
            for (int i = 0; i < 4; ++i)
                Opart[((size_t)slot * 128 + wave * 32 + mt * 16 + quad * 4 + i) * 64 + nt * 16 + m]
                    = f2b(o[mt][nt][i]);
        if (m == 0) {
            #pragma unroll
            for (int i = 0; i < 4; ++i)
                ml[(size_t)slot * 128 + wave * 32 + mt * 16 + quad * 4 + i] = lsum[mt][i];
        }
    }
}

// ---------------------------------------------------------------------------
// Merge s-split partials (max-free): O = sum_c O~_c / sum_c l_c.
// Block = (qt, h); thread t: row t/2, cols (t&1)*32 .. +32.
// ---------------------------------------------------------------------------
__global__ __launch_bounds__(256) void attn_merge(
    const unsigned short* __restrict__ Opart, const float* __restrict__ ml,
    unsigned short* __restrict__ attnb) {
    const int qt = blockIdx.x, h = blockIdx.y;
    const int nc = qt / 4 + 1;
    const int tid = threadIdx.x;
    const int r = tid >> 1, dh = (tid & 1) * 32;
    const int bs = (h * 16 + qt) * 4;

    float denom = 0.0f;
    #pragma unroll
    for (int c = 0; c < 4; ++c)
        if (c < nc) denom += ml[(size_t)(bs + c) * 128 + r];
    float inv = 1.0f / denom;

    float acc[32] = {};
    #pragma unroll
    for (int c = 0; c < 4; ++c) {
        if (c < nc) {
            const unsigned short* op = Opart + ((size_t)(bs + c) * 128 + r) * 64 + dh;
            #pragma unroll
            for (int j = 0; j < 4; ++j) {
                ushort8v v = *reinterpret_cast<const ushort8v*>(op + j * 8);
                #pragma unroll
                for (int k = 0; k < 8; ++k)
                    acc[j * 8 + k] += b2f(v[k]);
            }
        }
    }
    unsigned short* dst = attnb + (size_t)(qt * 128 + r) * 2048 + h * 64 + dh;
    #pragma unroll
    for (int j = 0; j < 4; ++j) {
        ushort8v v;
        #pragma unroll
        for (int k = 0; k < 8; ++k) v[k] = f2b(acc[j * 8 + k] * inv);
        *reinterpret_cast<ushort8v*>(dst + j * 8) = v;
    }
}

// ---------------------------------------------------------------------------
extern "C" void kernel_launch(void* const* d_in, const int* in_sizes, int n_in,
                              void* d_out, int out_size, void* d_ws, size_t ws_size,
                              hipStream_t stream) {
    const int*   positions = (const int*)d_in[0];
    const float* hidden    = (const float*)d_in[1];
    const float* Wqkv      = (const float*)d_in[2];
    const float* bqkv      = (const float*)d_in[3];
    const float* Wout      = (const float*)d_in[4];
    const float* bout      = (const float*)d_in[5];
    const float* tau_alpha = (const float*)d_in[6];
    const float* tau_wq    = (const float*)d_in[7];
    const float* tau_wv    = (const float*)d_in[8];

    unsigned char* ws = (unsigned char*)d_ws;
    unsigned short* P       = (unsigned short*)(ws);             // 25165824
    unsigned short* Opart   = (unsigned short*)(ws);             // reuses P (33.5MB)
    unsigned short* wqb     = (unsigned short*)(ws + 50331648);  // dead after GEMM1
    unsigned short* qh      = (unsigned short*)(ws + 50331648);
    unsigned short* kh      = (unsigned short*)(ws + 58720256);
    unsigned short* vpk     = (unsigned short*)(ws + 67108864);
    unsigned short* hb      = (unsigned short*)(ws + 75497472);  // dead after GEMM1
    float*          tok_raw = (float*)(ws + 75497472);           // after hb dead
    unsigned short* attnb   = (unsigned short*)(ws + 75497472);  // after tok_raw dead
    float*          ml      = (float*)(ws + 83886080);
    unsigned short* wob     = (unsigned short*)(ws + 85983232);

    // 0) fp32 -> bf16 conversions (one launch, 3 segments)
    cvt3_f32_bf16<<<10240, 256, 0, stream>>>(
        hidden, hb, 524288, Wqkv, wqb, 1572864, Wout, wob, 524288);
    // 1) QKV GEMM 256x192 tile, grid 32x8 = 256 blocks = full CU fill
    gemm_qkv_fg<<<dim3(32, 8), 512, 0, stream>>>(
        hb, wqb, bqkv, P, 2048, 6144, 2048);
    // 2) tok_raw = gelu(P) @ [tau_wq;tau_wv]^T  (split-K + atomics)
    hipMemsetAsync(tok_raw, 0, (size_t)2048 * 64 * 4, stream);
    tok_gemm_splitk<256><<<dim3(24, 32), 256, 0, stream>>>(
        P, tau_wq, tau_wv, tok_raw, 6144);
    // 3) gating + RoPE + layouts (vectorized; V fragment-packed)
    qkv_process<<<dim3(32, 32), 256, 0, stream>>>(
        P, tok_raw, tau_alpha, positions, qh, kh, vpk);
    // 4) s-split max-free flash attention, XCD-affine (1280 blocks)
    attn_fa<<<1280, 256, 0, stream>>>(qh, kh, vpk, Opart, ml);
    // 5) merge partials -> attnb
    attn_merge<<<dim3(16, 32), 256, 0, stream>>>(Opart, ml, attnb);
    // 6) out = attnb @ wob^T + bout  (64x64 tile -> 1024 blocks, 4/CU)
    gemm_bf16_bt<64, 64, false><<<dim3(32, 32), 256, 0, stream>>>(
        attnb, wob, bout, d_out, 2048, 2048, 2048);
}

// Round 11
// 347.133 us; speedup vs baseline: 1.1003x; 1.0593x over previous
//
#include <hip/hip_runtime.h>
#include <math.h>

// ---------------------------------------------------------------------------
// Moondream3Attention on MI355X (gfx950)
// T=2048, DIM=2048, H=32, HD=64, ROT=32, QKV_DIM=6144
// Pipeline (all-bf16 matmul datapath):  [R18: attn K/V frag-hoist + setprio]
//   0) cvt3: hidden->hb, Wqkv->wqb, Wout->wob (fp32->bf16, one launch)
//   1) qkv GEMM: 256x192 tile, BK=64, 512 thr, 4-phase counted-vmcnt,
//      grid 32x8 = 256 blocks = full CU fill (R9: dropped out of top-5)
//   2) tok = gelu(P) @ [tau_wq;tau_wv]^T   (split-K + atomics)
//   3) qkv_process (ushort8-vectorized): tau gating + RoPE;
//      V packed fragment-ordered: vpk[h][sb32][nt][quad][m][8]
//   4) attn_fa: s-split MAX-FREE flash attention, 1280 blocks.
//      R18: R9 PMC showed latency-bound (MfmaUtil 9.5, VALUBusy 22, HBM 7,
//      all low; VGPR=76 -> compiler serialized the per-sg K loads: 4x200cy
//      exposed L2 latency per s-step). Fix: bk[4][2]/bv[4] register arrays
//      (static idx) force all loads issued up-front + counted-vmcnt drain
//      under MFMA; s_setprio(1) around QKT/PV clusters (T5 attn regime).
//   5) attn_merge: O = sum_c O~_c / sum_c l_c -> attnb bf16
//   6) out = attnb @ wob^T + bout (64x64 tile, 1024 blocks, plain R4 form)
// Workspace (94,371,840 B), liveness-overlapped (unchanged from R10).
// ---------------------------------------------------------------------------

typedef __bf16 bf16x8 __attribute__((ext_vector_type(8)));
typedef float floatx4 __attribute__((ext_vector_type(4)));
typedef unsigned short ushort8v __attribute__((ext_vector_type(8)));

__device__ __forceinline__ unsigned short f2b(float x) {
    unsigned int b = __float_as_uint(x);
    b = b + 0x7FFFu + ((b >> 16) & 1u);   // round-to-nearest-even
    return (unsigned short)(b >> 16);
}
__device__ __forceinline__ unsigned short f2b_trunc(float x) {
    return (unsigned short)(__float_as_uint(x) >> 16);   // cheap, for P only
}
__device__ __forceinline__ float b2f(unsigned short u) {
    return __uint_as_float(((unsigned int)u) << 16);
}
__device__ __forceinline__ float gelu_f(float x) {
    return 0.5f * x * (1.0f + erff(x * 0.70710678118654752440f));
}
__device__ __forceinline__ float fexp2(float x) {
    return __builtin_amdgcn_exp2f(x);     // raw v_exp_f32; x=-1e30 -> 0
}
__device__ __forceinline__ floatx4 mfma16(bf16x8 a, bf16x8 b, floatx4 c) {
    return __builtin_amdgcn_mfma_f32_16x16x32_bf16(a, b, c, 0, 0, 0);
}
// async global->LDS, 16B per lane; lane i lands at ldsbase + i*16
__device__ __forceinline__ void gl2lds16(const unsigned short* g, unsigned short* l) {
    __builtin_amdgcn_global_load_lds(
        (__attribute__((address_space(1))) void*)g,
        (__attribute__((address_space(3))) void*)l, 16, 0, 0);
}

// inv_freq[i] = 1e6^(-i/16), i = 0..15
__constant__ float INV_FREQ[16] = {
    1.0f, 0.42169650342858224f, 0.17782794100389228f, 0.074989420933245582f,
    0.031622776601683791f, 0.013335214321633240f, 0.0056234132519034908f,
    0.0023713737056616552f, 0.001f, 4.2169650342858224e-4f,
    1.7782794100389228e-4f, 7.4989420933245582e-5f, 3.1622776601683791e-5f,
    1.3335214321633240e-5f, 5.6234132519034908e-6f, 2.3713737056616552e-6f
};

// s-chunk schedule, 128-q-row tiles: nc = qt/4+1 chunks of 512 s (last partial).
// Ordered longest-first: 24 full (8-step) chunks, then 16 finals by length.
__constant__ unsigned char CHUNK_QT[40] = {
    15,15,15, 14,14,14, 13,13,13, 12,12,12, 11,11, 10,10, 9,9, 8,8, 7,6,5,4,
    15,11,7,3, 14,10,6,2, 13,9,5,1, 12,8,4,0};
__constant__ unsigned char CHUNK_C[40] = {
    0,1,2, 0,1,2, 0,1,2, 0,1,2, 0,1, 0,1, 0,1, 0,1, 0,0,0,0,
    3,2,1,0, 3,2,1,0, 3,2,1,0, 3,2,1,0};

// ---------------------------------------------------------------------------
// One-launch fp32->bf16 conversion of three buffers.
// ---------------------------------------------------------------------------
__global__ __launch_bounds__(256) void cvt3_f32_bf16(
    const float* __restrict__ s0, unsigned short* __restrict__ d0, int n0,
    const float* __restrict__ s1, unsigned short* __restrict__ d1, int n1,
    const float* __restrict__ s2, unsigned short* __restrict__ d2, int n2) {
    int i = blockIdx.x * 256 + threadIdx.x;
    const float* s; unsigned short* d;
    if (i < n0)           { s = s0; d = d0; }
    else if (i < n0 + n1) { i -= n0; s = s1; d = d1; }
    else                  { i -= n0 + n1; s = s2; d = d2; if (i >= n2) return; }
    const float4* sp = reinterpret_cast<const float4*>(s) + (size_t)i * 2;
    float4 a = sp[0], b = sp[1];
    ushort8v r;
    r[0] = f2b(a.x); r[1] = f2b(a.y); r[2] = f2b(a.z); r[3] = f2b(a.w);
    r[4] = f2b(b.x); r[5] = f2b(b.y); r[6] = f2b(b.z); r[7] = f2b(b.w);
    *(reinterpret_cast<ushort8v*>(d) + i) = r;
}

// ---------------------------------------------------------------------------
// QKV GEMM, 256x192 tile, BK=64, 512 threads (8 waves as 2M x 4N, wave-tile
// 128x48 -> acc[8][3]).  Grid 32x8 = 256 blocks = exactly 1/CU (full fill).
// LDS per buffer (ushort offs): A0 @0 (8192), B0 @8192 (6144), A1 @14336
// (8192), B1 @22528 (6144); 2 buffers = 114688 B.  Subtiled layout per half:
// off(r, c4) = (r>>3)*256 + c4*64 + (r&7)*8 ushorts (conflict-free, meas 0).
// Staging: A-half (16KB) = 2 gl2lds/thread; B-half (12KB) = waves 0-3: 2,
// waves 4-7: 1 -> PER-WAVE vmcnt constants (w0-3: 6, w4-7: 5; drain 0 at
// kt==NT-2).  Full ledger + overwrite-liveness in R16 notes (verified R9).
// ---------------------------------------------------------------------------
__global__ __launch_bounds__(512, 1) void gemm_qkv_fg(
    const unsigned short* __restrict__ A, const unsigned short* __restrict__ B,
    const float* __restrict__ bias, unsigned short* __restrict__ P,
    int M, int N, int K) {
    __shared__ unsigned short Ls[2][28672];   // 2 x 56 KiB
    const int tid = threadIdx.x;
    const int wave = tid >> 6, lane = tid & 63;
    const int row16 = lane & 15, quad = lane >> 4;
    const int wrow = wave >> 2, wcol = wave & 3;     // 2 x 4 wave grid
    const int bm0 = blockIdx.y * 256, bn0 = blockIdx.x * 192;
    const int NT = K >> 6;

    floatx4 acc[8][3] = {};

    // stage one half: hf 0=A-ks0, 1=B-ks0, 2=A-ks1, 3=B-ks1
    auto stage_half = [&](int kt, int hf) {
        const bool isB = hf & 1;
        const unsigned short* mat = isB ? B : A;
        const int rbase = isB ? bn0 : bm0;
        const int colb = kt * 64 + (hf >> 1) * 32;
        unsigned short* dst = &Ls[kt & 1][(hf >> 1) * 14336 + (isB ? 8192 : 0)];
        if (isB) {
            {
                int g = tid;
                int rl = g & 7, c4 = (g >> 3) & 3, r8 = g >> 5;
                gl2lds16(mat + (size_t)(rbase + r8 * 8 + rl) * K + colb + c4 * 8,
                         dst + g * 8);
            }
            if (tid < 256) {                       // waves 0-3 only (uniform)
                int g = 512 + tid;
                int rl = g & 7, c4 = (g >> 3) & 3, r8 = g >> 5;
                gl2lds16(mat + (size_t)(rbase + r8 * 8 + rl) * K + colb + c4 * 8,
                         dst + g * 8);
            }
        } else {
            #pragma unroll
            for (int rd = 0; rd < 2; ++rd) {
                int g = tid + rd * 512;
                int rl = g & 7, c4 = (g >> 3) & 3, r8 = g >> 5;
                gl2lds16(mat + (size_t)(rbase + r8 * 8 + rl) * K + colb + c4 * 8,
                         dst + g * 8);
            }
        }
    };

    // prologue: tile0 {A0,B0,A1,B1} + tile1 {A0,B0,A1}; retire tile0
    stage_half(0, 0); stage_half(0, 1); stage_half(0, 2); stage_half(0, 3);
    stage_half(1, 0); stage_half(1, 1); stage_half(1, 2);
    if (wave < 4) asm volatile("s_waitcnt vmcnt(6)" ::: "memory");
    else          asm volatile("s_waitcnt vmcnt(5)" ::: "memory");
    __builtin_amdgcn_s_barrier();

    // per-thread fragment base offsets (ushorts within a half)
    const int ra = wrow * 128 + row16;
    const int rb = wcol * 48 + row16;
    const int aoff = (ra >> 3) * 256 + quad * 64 + (ra & 7) * 8;
    const int boff = (rb >> 3) * 256 + quad * 64 + (rb & 7) * 8;

    for (int kt = 0; kt < NT; ++kt) {
        const int bsel = kt & 1;
        bf16x8 af[8], bfr[3];
        // ---- phase 0: read A0[8]+B0[3]; stage B1(kt+1); MFMA mt0-3 ks0 ----
        #pragma unroll
        for (int mt = 0; mt < 8; ++mt)
            af[mt] = *reinterpret_cast<const bf16x8*>(&Ls[bsel][aoff + mt * 512]);
        #pragma unroll
        for (int j = 0; j < 3; ++j)
            bfr[j] = *reinterpret_cast<const bf16x8*>(&Ls[bsel][8192 + boff + j * 512]);
        if (kt + 1 < NT) stage_half(kt + 1, 3);
        __builtin_amdgcn_s_barrier();
        asm volatile("s_waitcnt lgkmcnt(0)" ::: "memory");
        __builtin_amdgcn_sched_barrier(0);
        __builtin_amdgcn_s_setprio(1);
        #pragma unroll
        for (int mt = 0; mt < 4; ++mt)
            #pragma unroll
            for (int j = 0; j < 3; ++j)
                acc[mt][j] = mfma16(af[mt], bfr[j], acc[mt][j]);
        __builtin_amdgcn_s_setprio(0);
        __builtin_amdgcn_s_barrier();
        // ---- phase 1: stage A0(kt+2); MFMA mt4-7 ks0 (af hi held) ----
        if (kt + 2 < NT) stage_half(kt + 2, 0);
        __builtin_amdgcn_sched_barrier(0);
        __builtin_amdgcn_s_setprio(1);
        #pragma unroll
        for (int mt = 0; mt < 4; ++mt)
            #pragma unroll
            for (int j = 0; j < 3; ++j)
                acc[4 + mt][j] = mfma16(af[4 + mt], bfr[j], acc[4 + mt][j]);
        __builtin_amdgcn_s_setprio(0);
        __builtin_amdgcn_s_barrier();
        // ---- phase 2: read A1[8]+B1[3]; stage B0(kt+2); MFMA mt0-3 ks1 ----
        #pragma unroll
        for (int mt = 0; mt < 8; ++mt)
            af[mt] = *reinterpret_cast<const bf16x8*>(&Ls[bsel][14336 + aoff + mt * 512]);
        #pragma unroll
        for (int j = 0; j < 3; ++j)
            bfr[j] = *reinterpret_cast<const bf16x8*>(&Ls[bsel][22528 + boff + j * 512]);
        if (kt + 2 < NT) stage_half(kt + 2, 1);
        __builtin_amdgcn_s_barrier();
        asm volatile("s_waitcnt lgkmcnt(0)" ::: "memory");
        __builtin_amdgcn_sched_barrier(0);
        __builtin_amdgcn_s_setprio(1);
        #pragma unroll
        for (int mt = 0; mt < 4; ++mt)
            #pragma unroll
            for (int j = 0; j < 3; ++j)
                acc[mt][j] = mfma16(af[mt], bfr[j], acc[mt][j]);
        __builtin_amdgcn_s_setprio(0);
        __builtin_amdgcn_s_barrier();
        // ---- phase 3: stage A1(kt+2); GATE; MFMA mt4-7 ks1 ----
        if (kt + 2 < NT) stage_half(kt + 2, 2);
        if (kt == NT - 2) {
            asm volatile("s_waitcnt vmcnt(0)" ::: "memory");
        } else if (kt < NT - 2) {
            if (wave < 4) asm volatile("s_waitcnt vmcnt(6)" ::: "memory");
            else          asm volatile("s_waitcnt vmcnt(5)" ::: "memory");
        }
        __builtin_amdgcn_sched_barrier(0);
        __builtin_amdgcn_s_setprio(1);
        #pragma unroll
        for (int mt = 0; mt < 4; ++mt)
            #pragma unroll
            for (int j = 0; j < 3; ++j)
                acc[4 + mt][j] = mfma16(af[4 + mt], bfr[j], acc[4 + mt][j]);
        __builtin_amdgcn_s_setprio(0);
        __builtin_amdgcn_s_barrier();
    }

    // epilogue: bias + bf16 store
    #pragma unroll
    for (int mt = 0; mt < 8; ++mt) {
        #pragma unroll
        for (int nt = 0; nt < 3; ++nt) {
            int gc = bn0 + wcol * 48 + nt * 16 + row16;
            float bv = bias[gc];
            int gr0 = bm0 + wrow * 128 + mt * 16 + quad * 4;
            #pragma unroll
            for (int i = 0; i < 4; ++i)
                P[(size_t)(gr0 + i) * N + gc] = f2b(acc[mt][nt][i] + bv);
        }
    }
}

// ---------------------------------------------------------------------------
// bf16 GEMM: C[M,N] = A[M,K] @ B[N,K]^T + bias[N].  BMxBN tile, BK=64.
// ---------------------------------------------------------------------------
template <int BM, int BN, bool OUT_BF16>
__global__ __launch_bounds__(256) void gemm_bf16_bt(
    const unsigned short* __restrict__ A, const unsigned short* __restrict__ B,
    const float* __restrict__ bias, void* __restrict__ Cout,
    int M, int N, int K) {
    constexpr int MT = BM / 32, NT = BN / 32;
    __shared__ unsigned short As[BM * 64];
    __shared__ unsigned short Bs[BN * 64];
    const int tid = threadIdx.x;
    const int wave = tid >> 6, lane = tid & 63;
    const int row16 = lane & 15, quad = lane >> 4;
    const int wm = (wave >> 1) * (BM / 2), wn = (wave & 1) * (BN / 2);
    const int bm0 = blockIdx.y * BM, bn0 = blockIdx.x * BN;
    const int rl = lane & 7, cl = lane >> 3;

    floatx4 acc[MT][NT] = {};

    for (int k0 = 0; k0 < K; k0 += 64) {
        __syncthreads();
        #pragma unroll
        for (int j = 0; j < BM / 32; ++j) {
            int unit = wave * (BM / 32) + j;
            const unsigned short* ga = A + (size_t)(bm0 + unit * 8 + rl) * K + k0 + cl * 8;
            gl2lds16(ga, &As[unit * 512 + lane * 8]);
        }
        #pragma unroll
        for (int j = 0; j < BN / 32; ++j) {
            int unit = wave * (BN / 32) + j;
            const unsigned short* gb = B + (size_t)(bn0 + unit * 8 + rl) * K + k0 + cl * 8;
            gl2lds16(gb, &Bs[unit * 512 + lane * 8]);
        }
        __syncthreads();

        #pragma unroll
        for (int ks = 0; ks < 2; ++ks) {
            bf16x8 af[MT], bfr[NT];
            #pragma unroll
            for (int mt = 0; mt < MT; ++mt) {
                int r = wm + mt * 16 + row16;
                af[mt] = *reinterpret_cast<const bf16x8*>(
                    &As[(r >> 3) * 512 + (ks * 4 + quad) * 64 + (r & 7) * 8]);
            }
            #pragma unroll
            for (int nt = 0; nt < NT; ++nt) {
                int r = wn + nt * 16 + row16;
                bfr[nt] = *reinterpret_cast<const bf16x8*>(
                    &Bs[(r >> 3) * 512 + (ks * 4 + quad) * 64 + (r & 7) * 8]);
            }
            #pragma unroll
            for (int mt = 0; mt < MT; ++mt)
                #pragma unroll
                for (int nt = 0; nt < NT; ++nt)
                    acc[mt][nt] = mfma16(af[mt], bfr[nt], acc[mt][nt]);
        }
    }

    #pragma unroll
    for (int mt = 0; mt < MT; ++mt) {
        #pragma unroll
        for (int nt = 0; nt < NT; ++nt) {
            int gc = bn0 + wn + nt * 16 + row16;
            float bv = bias[gc];
            int gr0 = bm0 + wm + mt * 16 + quad * 4;
            #pragma unroll
            for (int i = 0; i < 4; ++i) {
                float v = acc[mt][nt][i] + bv;
                if (OUT_BF16)
                    ((unsigned short*)Cout)[(size_t)(gr0 + i) * N + gc] = f2b(v);
                else
                    ((float*)Cout)[(size_t)(gr0 + i) * N + gc] = v;
            }
        }
    }
}

// ---------------------------------------------------------------------------
// tok GEMM split-K: C[2048,64] += gelu(P) @ [Bq;Bv]^T; C pre-zeroed.
// ---------------------------------------------------------------------------
template <int KSPLIT>
__global__ __launch_bounds__(256) void tok_gemm_splitk(
    const unsigned short* __restrict__ A0,
    const float* __restrict__ Bq, const float* __restrict__ Bv,
    float* __restrict__ C, int K) {
    constexpr int LDT = 72;
    __shared__ unsigned short As[64 * LDT];
    __shared__ unsigned short Bs[64 * LDT];
    const int tid = threadIdx.x;
    const int wave = tid >> 6, lane = tid & 63;
    const int row16 = lane & 15, quad = lane >> 4;
    const int wm = (wave >> 1) * 32, wn = (wave & 1) * 32;
    const int bm0 = blockIdx.y * 64;
    const int kbeg = blockIdx.x * KSPLIT;

    floatx4 acc[2][2] = {};

    for (int k0 = kbeg; k0 < kbeg + KSPLIT; k0 += 64) {
        #pragma unroll
        for (int it = 0; it < 2; ++it) {
            int i = tid + it * 256;
            int r = i >> 3, c8 = i & 7;
            size_t off = (size_t)(bm0 + r) * K + k0 + c8 * 8;
            ushort8v a0 = *reinterpret_cast<const ushort8v*>(A0 + off);
            ushort8v g;
            #pragma unroll
            for (int j = 0; j < 8; ++j) g[j] = f2b(gelu_f(b2f(a0[j])));
            *reinterpret_cast<ushort8v*>(&As[r * LDT + c8 * 8]) = g;

            const float* brow = (r < 32) ? (Bq + (size_t)r * K) : (Bv + (size_t)(r - 32) * K);
            float4 w0 = *reinterpret_cast<const float4*>(brow + k0 + c8 * 8);
            float4 w1 = *reinterpret_cast<const float4*>(brow + k0 + c8 * 8 + 4);
            ushort8v wb;
            wb[0] = f2b(w0.x); wb[1] = f2b(w0.y); wb[2] = f2b(w0.z); wb[3] = f2b(w0.w);
            wb[4] = f2b(w1.x); wb[5] = f2b(w1.y); wb[6] = f2b(w1.z); wb[7] = f2b(w1.w);
            *reinterpret_cast<ushort8v*>(&Bs[r * LDT + c8 * 8]) = wb;
        }
        __syncthreads();

        #pragma unroll
        for (int ks = 0; ks < 2; ++ks) {
            bf16x8 af[2], bfr[2];
            #pragma unroll
            for (int mt = 0; mt < 2; ++mt)
                af[mt] = *reinterpret_cast<const bf16x8*>(
                    &As[(wm + mt * 16 + row16) * LDT + ks * 32 + quad * 8]);
            #pragma unroll
            for (int nt = 0; nt < 2; ++nt)
                bfr[nt] = *reinterpret_cast<const bf16x8*>(
                    &Bs[(wn + nt * 16 + row16) * LDT + ks * 32 + quad * 8]);
            #pragma unroll
            for (int mt = 0; mt < 2; ++mt)
                #pragma unroll
                for (int nt = 0; nt < 2; ++nt)
                    acc[mt][nt] = mfma16(af[mt], bfr[nt], acc[mt][nt]);
        }
        __syncthreads();
    }

    #pragma unroll
    for (int mt = 0; mt < 2; ++mt)
        #pragma unroll
        for (int nt = 0; nt < 2; ++nt) {
            int gc = wn + nt * 16 + row16;
            int gr0 = bm0 + wm + mt * 16 + quad * 4;
            #pragma unroll
            for (int i = 0; i < 4; ++i)
                atomicAdd(&C[(size_t)(gr0 + i) * 64 + gc], acc[mt][nt][i]);
        }
}

// ---------------------------------------------------------------------------
// tau gating + RoPE + layout transforms; qkv = P (bf16, bias included).
// V is packed fragment-ordered: vpk[h][sb32][nt][quad][m][8] where
// element = V[d=nt*16+m][s=sb*32+quad*8+j] -> attn B-frag load is
// base + lane*16B (fully coalesced). q pre-scaled by 0.125*log2e.
// ---------------------------------------------------------------------------
__global__ __launch_bounds__(256) void qkv_process(
    const unsigned short* __restrict__ P,
    const float* __restrict__ tok_raw, const float* __restrict__ tau_alpha,
    const int* __restrict__ positions, unsigned short* __restrict__ qh,
    unsigned short* __restrict__ kh, unsigned short* __restrict__ vpk) {
    const int h = blockIdx.y;
    const int t0 = blockIdx.x * 64;
    const int tid = threadIdx.x;
    __shared__ float vtr[64][65];
    __shared__ float tauq_s[64], tauv_s[64];

    if (tid < 64) {
        int t = t0 + tid;
        float pos = (float)positions[t];
        float pl = logf(fmaxf(pos + 1.0f, 1e-6f));
        float a = tau_alpha[h];
        float tp = 0.5f + 1.0f / (1.0f + __expf(-a * pl));
        tauq_s[tid] = tanhf(tok_raw[t * 64 + h]) + tp;
        tauv_s[tid] = tanhf(tok_raw[t * 64 + 32 + h]) + tp;
    }
    __syncthreads();

    const float QSCALE = 0.18033688011112042f;   // 0.125 * log2(e)
    #pragma unroll
    for (int it = 0; it < 2; ++it) {
        int idx = tid + it * 256;
        int tl = idx >> 3, c8 = idx & 7;
        int t = t0 + tl;
        size_t rb = (size_t)t * 6144 + h * 64 + c8 * 8;
        ushort8v q0v = *reinterpret_cast<const ushort8v*>(P + rb);
        ushort8v k0v = *reinterpret_cast<const ushort8v*>(P + rb + 2048);
        ushort8v v0v = *reinterpret_cast<const ushort8v*>(P + rb + 4096);
        float tq = tauq_s[tl], tv = tauv_s[tl];
        float qo[8], ko[8];
        #pragma unroll
        for (int j = 0; j < 8; ++j) {
            qo[j] = b2f(q0v[j]) * tq;
            ko[j] = b2f(k0v[j]);
        }
        if (c8 < 4) {                          // rotary chunks 0..3
            size_t rp = (size_t)t * 6144 + h * 64 + (c8 ^ 2) * 8;
            ushort8v qp0 = *reinterpret_cast<const ushort8v*>(P + rp);
            ushort8v kp0 = *reinterpret_cast<const ushort8v*>(P + rp + 2048);
            float pos = (float)positions[t];
            float sgn = (c8 < 2) ? -1.0f : 1.0f;
            #pragma unroll
            for (int j = 0; j < 8; ++j) {
                int fi = (c8 * 8 + j) & 15;
                float ang = pos * INV_FREQ[fi];
                float s, c;
                sincosf(ang, &s, &c);
                float qp = b2f(qp0[j]) * tq;
                float kp = b2f(kp0[j]);
                qo[j] = qo[j] * c + sgn * qp * s;
                ko[j] = ko[j] * c + sgn * kp * s;
            }
        }
        size_t ob = ((size_t)h * 2048 + t) * 64 + c8 * 8;
        ushort8v qw, kw;
        #pragma unroll
        for (int j = 0; j < 8; ++j) {
            qw[j] = f2b(qo[j] * QSCALE);
            kw[j] = f2b(ko[j]);
        }
        *reinterpret_cast<ushort8v*>(qh + ob) = qw;
        *reinterpret_cast<ushort8v*>(kh + ob) = kw;
        #pragma unroll
        for (int j = 0; j < 8; ++j)
            vtr[c8 * 8 + j][tl] = b2f(v0v[j]) * tv;
    }
    __syncthreads();
    // V pack: vpk[h][sb32][nt][quad][m][8] = V[d=nt*16+m][s=sb*32+quad*8+j]
    #pragma unroll
    for (int it = 0; it < 2; ++it) {
        int idx = tid + it * 256;
        int d = idx >> 3, tc = (idx & 7) * 8;      // s-chunk [t0+tc, t0+tc+8)
        int sb = (t0 + tc) >> 5;
        int quad = (tc & 31) >> 3;
        int nt = d >> 4, m = d & 15;
        ushort8v w;
        #pragma unroll
        for (int j = 0; j < 8; ++j) w[j] = f2b(vtr[d][tc + j]);
        *reinterpret_cast<ushort8v*>(
            vpk + (size_t)h * 131072 + sb * 2048 + nt * 512 + quad * 128 + m * 8) = w;
    }
}

// ---------------------------------------------------------------------------
// s-split MAX-FREE flash attention, XCD-affine 1D schedule (R9 config).
// b&7 = XCD slot; head = (b&7) + 8*((b>>3)&3) -> 4 heads per XCD. cpos=b>>5
// walks 40 chunks longest-first. Wave owns 32 q-rows (2 m-frags).
// P = 2^s directly (scale folded into qh); masked -> 0.
// R18: bk[4][2]/bv[4] register arrays (static indices) force the compiler
// to issue all K/V loads up-front and drain with counted vmcnt under the
// MFMA clusters (R9 PMC: VGPR=76 -> loads were serialized, ~200cy L2
// latency exposed 4x per s-step); s_setprio(1) wraps QKT and PV clusters
// (T5, +4-7% measured on attn with independent waves).
// ---------------------------------------------------------------------------
__global__ __launch_bounds__(256) void attn_fa(
    const unsigned short* __restrict__ qh, const unsigned short* __restrict__ kh,
    const unsigned short* __restrict__ vpk, unsigned short* __restrict__ Opart,
    float* __restrict__ ml) {
    constexpr int LD = 72;
    __shared__ unsigned short pbuf[4][2][16 * LD];   // [wave][mt]
    const int b = blockIdx.x;
    const int h = (b & 7) + 8 * ((b >> 3) & 3);
    const int cpos = b >> 5;
    const int qt = CHUNK_QT[cpos], ch = CHUNK_C[cpos];
    const int q0 = qt * 128;
    const int slot = (h * 16 + qt) * 4 + ch;
    const int wave = threadIdx.x >> 6, lane = threadIdx.x & 63;
    const int m = lane & 15, quad = lane >> 4;
    const int qrow0 = q0 + wave * 32;
    const int sbeg = ch * 512;
    const int send = min(sbeg + 512, qrow0 + 32);

    bf16x8 aq[2][2];
    #pragma unroll
    for (int mt = 0; mt < 2; ++mt) {
        const unsigned short* qptr = qh + ((size_t)h * 2048 + qrow0 + mt * 16 + m) * 64;
        aq[mt][0] = *reinterpret_cast<const bf16x8*>(qptr + quad * 8);
        aq[mt][1] = *reinterpret_cast<const bf16x8*>(qptr + 32 + quad * 8);
    }
    const unsigned short* kbase = kh + (size_t)h * 2048 * 64;
    const unsigned short* vbase = vpk + (size_t)h * 131072;

    floatx4 o[2][4] = {};
    float lsum[2][4] = {};

    for (int s0 = sbeg; s0 < send; s0 += 64) {
        // ---- K loads: all 8 b128 issued up-front (bk[4][2] held in regs) ----
        bf16x8 bk[4][2];
        #pragma unroll
        for (int sg = 0; sg < 4; ++sg) {
            const unsigned short* kr = kbase + (size_t)(s0 + sg * 16 + m) * 64;
            bk[sg][0] = *reinterpret_cast<const bf16x8*>(kr + quad * 8);
            bk[sg][1] = *reinterpret_cast<const bf16x8*>(kr + 32 + quad * 8);
        }
        floatx4 sc[2][4];
        __builtin_amdgcn_s_setprio(1);
        #pragma unroll
        for (int sg = 0; sg < 4; ++sg) {
            #pragma unroll
            for (int mt = 0; mt < 2; ++mt) {
                floatx4 z = {};
                z = mfma16(aq[mt][0], bk[sg][0], z);
                z = mfma16(aq[mt][1], bk[sg][1], z);
                sc[mt][sg] = z;
            }
        }
        __builtin_amdgcn_s_setprio(0);
        if (s0 + 63 > qrow0) {               // only near-diagonal steps mask
            #pragma unroll
            for (int mt = 0; mt < 2; ++mt)
                #pragma unroll
                for (int sg = 0; sg < 4; ++sg)
                    #pragma unroll
                    for (int i = 0; i < 4; ++i) {
                        int t = qrow0 + mt * 16 + quad * 4 + i;
                        int s = s0 + sg * 16 + m;
                        sc[mt][sg][i] = (s > t) ? -1e30f : sc[mt][sg][i];
                    }
        }
        // P = 2^s directly (max-free, scale pre-folded); masked -> 0
        #pragma unroll
        for (int mt = 0; mt < 2; ++mt)
            #pragma unroll
            for (int sg = 0; sg < 4; ++sg)
                #pragma unroll
                for (int i = 0; i < 4; ++i)
                    sc[mt][sg][i] = fexp2(sc[mt][sg][i]);
        #pragma unroll
        for (int mt = 0; mt < 2; ++mt)
            #pragma unroll
            for (int i = 0; i < 4; ++i)
                lsum[mt][i] += (sc[mt][0][i] + sc[mt][1][i]) + (sc[mt][2][i] + sc[mt][3][i]);

        // P: C-layout regs -> wave-private LDS -> A-layout frags (no barrier)
        unsigned short* pb0 = pbuf[wave][0];
        unsigned short* pb1 = pbuf[wave][1];
        #pragma unroll
        for (int sg = 0; sg < 4; ++sg)
            #pragma unroll
            for (int i = 0; i < 4; ++i) {
                pb0[(quad * 4 + i) * LD + sg * 16 + m] = f2b_trunc(sc[0][sg][i]);
                pb1[(quad * 4 + i) * LD + sg * 16 + m] = f2b_trunc(sc[1][sg][i]);
            }
        bf16x8 ap[2][2];
        #pragma unroll
        for (int mt = 0; mt < 2; ++mt) {
            ap[mt][0] = *reinterpret_cast<const bf16x8*>(&pbuf[wave][mt][m * LD + quad * 8]);
            ap[mt][1] = *reinterpret_cast<const bf16x8*>(&pbuf[wave][mt][m * LD + 32 + quad * 8]);
        }
        #pragma unroll
        for (int c = 0; c < 2; ++c) {
            const unsigned short* vrow = vbase + ((s0 >> 5) + c) * 2048;
            bf16x8 bv[4];
            #pragma unroll
            for (int nt = 0; nt < 4; ++nt)
                bv[nt] = *reinterpret_cast<const bf16x8*>(vrow + nt * 512 + lane * 8);
            __builtin_amdgcn_s_setprio(1);
            #pragma unroll
            for (int nt = 0; nt < 4; ++nt) {
                o[0][nt] = mfma16(ap[0][c], bv[nt], o[0][nt]);
                o[1][nt] = mfma16(ap[1][c], bv[nt], o[1][nt]);
            }
            __builtin_amdgcn_s_setprio(0);
        }
    }

    // epilogue: reduce l across the 16 column-lanes, store partials
    #pragma unroll
    for (int d = 1; d < 16; d <<= 1)
        #pragma unroll
        for (int mt = 0; mt < 2; ++mt)
            #pragma unroll
            for (int i = 0; i < 4; ++i)
                lsum[mt][i] += __shfl_xor(lsum[mt][i], d, 16);
    #pragma unroll
    for (int mt = 0; mt < 2; ++mt) {
        #pragma unroll
        for (int nt = 0; nt < 4; ++nt)
            #pragma unroll
            for (int i = 0; i < 4; ++i)
                Opart[((size_t)slot * 128 + wave * 32 + mt * 16 + quad * 4 + i) * 64 + nt * 16 + m]
                    = f2b(o[mt][nt][i]);
        if (m == 0) {
            #pragma unroll
            for (int i = 0; i < 4; ++i)
                ml[(size_t)slot * 128 + wave * 32 + mt * 16 + quad * 4 + i] = lsum[mt][i];
        }
    }
}

// ---------------------------------------------------------------------------
// Merge s-split partials (max-free): O = sum_c O~_c / sum_c l_c.
// Block = (qt, h); thread t: row t/2, cols (t&1)*32 .. +32.
// ---------------------------------------------------------------------------
__global__ __launch_bounds__(256) void attn_merge(
    const unsigned short* __restrict__ Opart, const float* __restrict__ ml,
    unsigned short* __restrict__ attnb) {
    const int qt = blockIdx.x, h = blockIdx.y;
    const int nc = qt / 4 + 1;
    const int tid = threadIdx.x;
    const int r = tid >> 1, dh = (tid & 1) * 32;
    const int bs = (h * 16 + qt) * 4;

    float denom = 0.0f;
    #pragma unroll
    for (int c = 0; c < 4; ++c)
        if (c < nc) denom += ml[(size_t)(bs + c) * 128 + r];
    float inv = 1.0f / denom;

    float acc[32] = {};
    #pragma unroll
    for (int c = 0; c < 4; ++c) {
        if (c < nc) {
            const unsigned short* op = Opart + ((size_t)(bs + c) * 128 + r) * 64 + dh;
            #pragma unroll
            for (int j = 0; j < 4; ++j) {
                ushort8v v = *reinterpret_cast<const ushort8v*>(op + j * 8);
                #pragma unroll
                for (int k = 0; k < 8; ++k)
                    acc[j * 8 + k] += b2f(v[k]);
            }
        }
    }
    unsigned short* dst = attnb + (size_t)(qt * 128 + r) * 2048 + h * 64 + dh;
    #pragma unroll
    for (int j = 0; j < 4; ++j) {
        ushort8v v;
        #pragma unroll
        for (int k = 0; k < 8; ++k) v[k] = f2b(acc[j * 8 + k] * inv);
        *reinterpret_cast<ushort8v*>(dst + j * 8) = v;
    }
}

// ---------------------------------------------------------------------------
extern "C" void kernel_launch(void* const* d_in, const int* in_sizes, int n_in,
                              void* d_out, int out_size, void* d_ws, size_t ws_size,
                              hipStream_t stream) {
    const int*   positions = (const int*)d_in[0];
    const float* hidden    = (const float*)d_in[1];
    const float* Wqkv      = (const float*)d_in[2];
    const float* bqkv      = (const float*)d_in[3];
    const float* Wout      = (const float*)d_in[4];
    const float* bout      = (const float*)d_in[5];
    const float* tau_alpha = (const float*)d_in[6];
    const float* tau_wq    = (const float*)d_in[7];
    const float* tau_wv    = (const float*)d_in[8];

    unsigned char* ws = (unsigned char*)d_ws;
    unsigned short* P       = (unsigned short*)(ws);             // 25165824
    unsigned short* Opart   = (unsigned short*)(ws);             // reuses P (33.5MB)
    unsigned short* wqb     = (unsigned short*)(ws + 50331648);  // dead after GEMM1
    unsigned short* qh      = (unsigned short*)(ws + 50331648);
    unsigned short* kh      = (unsigned short*)(ws + 58720256);
    unsigned short* vpk     = (unsigned short*)(ws + 67108864);
    unsigned short* hb      = (unsigned short*)(ws + 75497472);  // dead after GEMM1
    float*          tok_raw = (float*)(ws + 75497472);           // after hb dead
    unsigned short* attnb   = (unsigned short*)(ws + 75497472);  // after tok_raw dead
    float*          ml      = (float*)(ws + 83886080);
    unsigned short* wob     = (unsigned short*)(ws + 85983232);

    // 0) fp32 -> bf16 conversions (one launch, 3 segments)
    cvt3_f32_bf16<<<10240, 256, 0, stream>>>(
        hidden, hb, 524288, Wqkv, wqb, 1572864, Wout, wob, 524288);
    // 1) QKV GEMM 256x192 tile, grid 32x8 = 256 blocks = full CU fill
    gemm_qkv_fg<<<dim3(32, 8), 512, 0, stream>>>(
        hb, wqb, bqkv, P, 2048, 6144, 2048);
    // 2) tok_raw = gelu(P) @ [tau_wq;tau_wv]^T  (split-K + atomics)
    hipMemsetAsync(tok_raw, 0, (size_t)2048 * 64 * 4, stream);
    tok_gemm_splitk<256><<<dim3(24, 32), 256, 0, stream>>>(
        P, tau_wq, tau_wv, tok_raw, 6144);
    // 3) gating + RoPE + layouts (vectorized; V fragment-packed)
    qkv_process<<<dim3(32, 32), 256, 0, stream>>>(
        P, tok_raw, tau_alpha, positions, qh, kh, vpk);
    // 4) s-split max-free flash attention, XCD-affine (1280 blocks)
    attn_fa<<<1280, 256, 0, stream>>>(qh, kh, vpk, Opart, ml);
    // 5) merge partials -> attnb
    attn_merge<<<dim3(16, 32), 256, 0, stream>>>(Opart, ml, attnb);
    // 6) out = attnb @ wob^T + bout  (64x64 tile -> 1024 blocks, 4/CU)
    gemm_bf16_bt<64, 64, false><<<dim3(32, 32), 256, 0, stream>>>(
        attnb, wob, bout, d_out, 2048, 2048, 2048);
}

// Round 12
// 321.689 us; speedup vs baseline: 1.1873x; 1.0791x over previous
//
#include <hip/hip_runtime.h>
#include <math.h>

// ---------------------------------------------------------------------------
// Moondream3Attention on MI355X (gfx950)
// T=2048, DIM=2048, H=32, HD=64, ROT=32, QKV_DIM=6144
// Pipeline (all-bf16 matmul datapath):  [R20: out-proj ported to fg schedule]
//   0) cvt3: hidden->hb, Wqkv->wqb, Wout->wob (fp32->bf16, one launch)
//   1) qkv GEMM: 256x192 tile, BK=64, 512 thr, 4-phase counted-vmcnt,
//      grid 32x8 = 256 blocks = full CU fill (R11: 69.2us, 744 TF, 38%)
//   2) tok = gelu(P) @ [tau_wq;tau_wv]^T   (split-K + atomics)
//   3) qkv_process (ushort8-vectorized): tau gating + RoPE;
//      V packed fragment-ordered: vpk[h][sb32][nt][quad][m][8]
//   4) attn_fa: s-split MAX-FREE flash attention, 1280 blocks
//      (R11: frag-hoist + setprio verified, dropped out of top-5)
//   5) attn_merge: O = sum_c O~_c / sum_c l_c -> attnb bf16
//   6) out = attnb @ wob^T + bout: gemm_out_fg 128x128 tile, BK=64,
//      256 thr (2x2 waves, 64x64/wave), 4-phase counted-vmcnt(6), grid
//      16x16 = 256 blocks full fill — the R9/R11-verified fg schedule
//      (replaces the 2-barrier 64^2 template, est. 60-80 -> ~30-40us).
// Workspace (94,371,840 B), liveness-overlapped (unchanged from R10).
// ---------------------------------------------------------------------------

typedef __bf16 bf16x8 __attribute__((ext_vector_type(8)));
typedef float floatx4 __attribute__((ext_vector_type(4)));
typedef unsigned short ushort8v __attribute__((ext_vector_type(8)));

__device__ __forceinline__ unsigned short f2b(float x) {
    unsigned int b = __float_as_uint(x);
    b = b + 0x7FFFu + ((b >> 16) & 1u);   // round-to-nearest-even
    return (unsigned short)(b >> 16);
}
__device__ __forceinline__ unsigned short f2b_trunc(float x) {
    return (unsigned short)(__float_as_uint(x) >> 16);   // cheap, for P only
}
__device__ __forceinline__ float b2f(unsigned short u) {
    return __uint_as_float(((unsigned int)u) << 16);
}
__device__ __forceinline__ float gelu_f(float x) {
    return 0.5f * x * (1.0f + erff(x * 0.70710678118654752440f));
}
__device__ __forceinline__ float fexp2(float x) {
    return __builtin_amdgcn_exp2f(x);     // raw v_exp_f32; x=-1e30 -> 0
}
__device__ __forceinline__ floatx4 mfma16(bf16x8 a, bf16x8 b, floatx4 c) {
    return __builtin_amdgcn_mfma_f32_16x16x32_bf16(a, b, c, 0, 0, 0);
}
// async global->LDS, 16B per lane; lane i lands at ldsbase + i*16
__device__ __forceinline__ void gl2lds16(const unsigned short* g, unsigned short* l) {
    __builtin_amdgcn_global_load_lds(
        (__attribute__((address_space(1))) void*)g,
        (__attribute__((address_space(3))) void*)l, 16, 0, 0);
}

// inv_freq[i] = 1e6^(-i/16), i = 0..15
__constant__ float INV_FREQ[16] = {
    1.0f, 0.42169650342858224f, 0.17782794100389228f, 0.074989420933245582f,
    0.031622776601683791f, 0.013335214321633240f, 0.0056234132519034908f,
    0.0023713737056616552f, 0.001f, 4.2169650342858224e-4f,
    1.7782794100389228e-4f, 7.4989420933245582e-5f, 3.1622776601683791e-5f,
    1.3335214321633240e-5f, 5.6234132519034908e-6f, 2.3713737056616552e-6f
};

// s-chunk schedule, 128-q-row tiles: nc = qt/4+1 chunks of 512 s (last partial).
// Ordered longest-first: 24 full (8-step) chunks, then 16 finals by length.
__constant__ unsigned char CHUNK_QT[40] = {
    15,15,15, 14,14,14, 13,13,13, 12,12,12, 11,11, 10,10, 9,9, 8,8, 7,6,5,4,
    15,11,7,3, 14,10,6,2, 13,9,5,1, 12,8,4,0};
__constant__ unsigned char CHUNK_C[40] = {
    0,1,2, 0,1,2, 0,1,2, 0,1,2, 0,1, 0,1, 0,1, 0,1, 0,0,0,0,
    3,2,1,0, 3,2,1,0, 3,2,1,0, 3,2,1,0};

// ---------------------------------------------------------------------------
// One-launch fp32->bf16 conversion of three buffers.
// ---------------------------------------------------------------------------
__global__ __launch_bounds__(256) void cvt3_f32_bf16(
    const float* __restrict__ s0, unsigned short* __restrict__ d0, int n0,
    const float* __restrict__ s1, unsigned short* __restrict__ d1, int n1,
    const float* __restrict__ s2, unsigned short* __restrict__ d2, int n2) {
    int i = blockIdx.x * 256 + threadIdx.x;
    const float* s; unsigned short* d;
    if (i < n0)           { s = s0; d = d0; }
    else if (i < n0 + n1) { i -= n0; s = s1; d = d1; }
    else                  { i -= n0 + n1; s = s2; d = d2; if (i >= n2) return; }
    const float4* sp = reinterpret_cast<const float4*>(s) + (size_t)i * 2;
    float4 a = sp[0], b = sp[1];
    ushort8v r;
    r[0] = f2b(a.x); r[1] = f2b(a.y); r[2] = f2b(a.z); r[3] = f2b(a.w);
    r[4] = f2b(b.x); r[5] = f2b(b.y); r[6] = f2b(b.z); r[7] = f2b(b.w);
    *(reinterpret_cast<ushort8v*>(d) + i) = r;
}

// ---------------------------------------------------------------------------
// QKV GEMM, 256x192 tile, BK=64, 512 threads (8 waves as 2M x 4N, wave-tile
// 128x48 -> acc[8][3]).  Grid 32x8 = 256 blocks = exactly 1/CU (full fill).
// LDS per buffer (ushort offs): A0 @0 (8192), B0 @8192 (6144), A1 @14336
// (8192), B1 @22528 (6144); 2 buffers = 114688 B.  Subtiled layout per half:
// off(r, c4) = (r>>3)*256 + c4*64 + (r&7)*8 ushorts (conflict-free, meas 0).
// Staging: A-half (16KB) = 2 gl2lds/thread; B-half (12KB) = waves 0-3: 2,
// waves 4-7: 1 -> PER-WAVE vmcnt constants (w0-3: 6, w4-7: 5; drain 0 at
// kt==NT-2).  Full ledger + overwrite-liveness in R16 notes (verified R9/R11).
// ---------------------------------------------------------------------------
__global__ __launch_bounds__(512, 1) void gemm_qkv_fg(
    const unsigned short* __restrict__ A, const unsigned short* __restrict__ B,
    const float* __restrict__ bias, unsigned short* __restrict__ P,
    int M, int N, int K) {
    __shared__ unsigned short Ls[2][28672];   // 2 x 56 KiB
    const int tid = threadIdx.x;
    const int wave = tid >> 6, lane = tid & 63;
    const int row16 = lane & 15, quad = lane >> 4;
    const int wrow = wave >> 2, wcol = wave & 3;     // 2 x 4 wave grid
    const int bm0 = blockIdx.y * 256, bn0 = blockIdx.x * 192;
    const int NT = K >> 6;

    floatx4 acc[8][3] = {};

    // stage one half: hf 0=A-ks0, 1=B-ks0, 2=A-ks1, 3=B-ks1
    auto stage_half = [&](int kt, int hf) {
        const bool isB = hf & 1;
        const unsigned short* mat = isB ? B : A;
        const int rbase = isB ? bn0 : bm0;
        const int colb = kt * 64 + (hf >> 1) * 32;
        unsigned short* dst = &Ls[kt & 1][(hf >> 1) * 14336 + (isB ? 8192 : 0)];
        if (isB) {
            {
                int g = tid;
                int rl = g & 7, c4 = (g >> 3) & 3, r8 = g >> 5;
                gl2lds16(mat + (size_t)(rbase + r8 * 8 + rl) * K + colb + c4 * 8,
                         dst + g * 8);
            }
            if (tid < 256) {                       // waves 0-3 only (uniform)
                int g = 512 + tid;
                int rl = g & 7, c4 = (g >> 3) & 3, r8 = g >> 5;
                gl2lds16(mat + (size_t)(rbase + r8 * 8 + rl) * K + colb + c4 * 8,
                         dst + g * 8);
            }
        } else {
            #pragma unroll
            for (int rd = 0; rd < 2; ++rd) {
                int g = tid + rd * 512;
                int rl = g & 7, c4 = (g >> 3) & 3, r8 = g >> 5;
                gl2lds16(mat + (size_t)(rbase + r8 * 8 + rl) * K + colb + c4 * 8,
                         dst + g * 8);
            }
        }
    };

    // prologue: tile0 {A0,B0,A1,B1} + tile1 {A0,B0,A1}; retire tile0
    stage_half(0, 0); stage_half(0, 1); stage_half(0, 2); stage_half(0, 3);
    stage_half(1, 0); stage_half(1, 1); stage_half(1, 2);
    if (wave < 4) asm volatile("s_waitcnt vmcnt(6)" ::: "memory");
    else          asm volatile("s_waitcnt vmcnt(5)" ::: "memory");
    __builtin_amdgcn_s_barrier();

    // per-thread fragment base offsets (ushorts within a half)
    const int ra = wrow * 128 + row16;
    const int rb = wcol * 48 + row16;
    const int aoff = (ra >> 3) * 256 + quad * 64 + (ra & 7) * 8;
    const int boff = (rb >> 3) * 256 + quad * 64 + (rb & 7) * 8;

    for (int kt = 0; kt < NT; ++kt) {
        const int bsel = kt & 1;
        bf16x8 af[8], bfr[3];
        // ---- phase 0: read A0[8]+B0[3]; stage B1(kt+1); MFMA mt0-3 ks0 ----
        #pragma unroll
        for (int mt = 0; mt < 8; ++mt)
            af[mt] = *reinterpret_cast<const bf16x8*>(&Ls[bsel][aoff + mt * 512]);
        #pragma unroll
        for (int j = 0; j < 3; ++j)
            bfr[j] = *reinterpret_cast<const bf16x8*>(&Ls[bsel][8192 + boff + j * 512]);
        if (kt + 1 < NT) stage_half(kt + 1, 3);
        __builtin_amdgcn_s_barrier();
        asm volatile("s_waitcnt lgkmcnt(0)" ::: "memory");
        __builtin_amdgcn_sched_barrier(0);
        __builtin_amdgcn_s_setprio(1);
        #pragma unroll
        for (int mt = 0; mt < 4; ++mt)
            #pragma unroll
            for (int j = 0; j < 3; ++j)
                acc[mt][j] = mfma16(af[mt], bfr[j], acc[mt][j]);
        __builtin_amdgcn_s_setprio(0);
        __builtin_amdgcn_s_barrier();
        // ---- phase 1: stage A0(kt+2); MFMA mt4-7 ks0 (af hi held) ----
        if (kt + 2 < NT) stage_half(kt + 2, 0);
        __builtin_amdgcn_sched_barrier(0);
        __builtin_amdgcn_s_setprio(1);
        #pragma unroll
        for (int mt = 0; mt < 4; ++mt)
            #pragma unroll
            for (int j = 0; j < 3; ++j)
                acc[4 + mt][j] = mfma16(af[4 + mt], bfr[j], acc[4 + mt][j]);
        __builtin_amdgcn_s_setprio(0);
        __builtin_amdgcn_s_barrier();
        // ---- phase 2: read A1[8]+B1[3]; stage B0(kt+2); MFMA mt0-3 ks1 ----
        #pragma unroll
        for (int mt = 0; mt < 8; ++mt)
            af[mt] = *reinterpret_cast<const bf16x8*>(&Ls[bsel][14336 + aoff + mt * 512]);
        #pragma unroll
        for (int j = 0; j < 3; ++j)
            bfr[j] = *reinterpret_cast<const bf16x8*>(&Ls[bsel][22528 + boff + j * 512]);
        if (kt + 2 < NT) stage_half(kt + 2, 1);
        __builtin_amdgcn_s_barrier();
        asm volatile("s_waitcnt lgkmcnt(0)" ::: "memory");
        __builtin_amdgcn_sched_barrier(0);
        __builtin_amdgcn_s_setprio(1);
        #pragma unroll
        for (int mt = 0; mt < 4; ++mt)
            #pragma unroll
            for (int j = 0; j < 3; ++j)
                acc[mt][j] = mfma16(af[mt], bfr[j], acc[mt][j]);
        __builtin_amdgcn_s_setprio(0);
        __builtin_amdgcn_s_barrier();
        // ---- phase 3: stage A1(kt+2); GATE; MFMA mt4-7 ks1 ----
        if (kt + 2 < NT) stage_half(kt + 2, 2);
        if (kt == NT - 2) {
            asm volatile("s_waitcnt vmcnt(0)" ::: "memory");
        } else if (kt < NT - 2) {
            if (wave < 4) asm volatile("s_waitcnt vmcnt(6)" ::: "memory");
            else          asm volatile("s_waitcnt vmcnt(5)" ::: "memory");
        }
        __builtin_amdgcn_sched_barrier(0);
        __builtin_amdgcn_s_setprio(1);
        #pragma unroll
        for (int mt = 0; mt < 4; ++mt)
            #pragma unroll
            for (int j = 0; j < 3; ++j)
                acc[4 + mt][j] = mfma16(af[4 + mt], bfr[j], acc[4 + mt][j]);
        __builtin_amdgcn_s_setprio(0);
        __builtin_amdgcn_s_barrier();
    }

    // epilogue: bias + bf16 store
    #pragma unroll
    for (int mt = 0; mt < 8; ++mt) {
        #pragma unroll
        for (int nt = 0; nt < 3; ++nt) {
            int gc = bn0 + wcol * 48 + nt * 16 + row16;
            float bv = bias[gc];
            int gr0 = bm0 + wrow * 128 + mt * 16 + quad * 4;
            #pragma unroll
            for (int i = 0; i < 4; ++i)
                P[(size_t)(gr0 + i) * N + gc] = f2b(acc[mt][nt][i] + bv);
        }
    }
}

// ---------------------------------------------------------------------------
// Out-projection GEMM: C[M,N] = A[M,K] @ B[N,K]^T + bias, fp32 out.
// 128x128 tile, BK=64, 256 threads (4 waves as 2x2, wave-tile 64x64,
// acc[4][4]).  Grid 16x16 = 256 blocks = full CU fill.  Same 4-phase
// counted-vmcnt/lgkm/setprio schedule as gemm_qkv_fg (R9/R11-verified).
// LDS halves (ushort offs): A0 @0, B0 @4096, A1 @8192, B1 @12288, each
// 4096 ushorts (128 rows x 32 cols); 2 buffers = 65536 B.
// Staging: every half = 2 gl2lds/thread (uniform) -> vmcnt(6) constant.
// Ledger: prologue tile0 (8) + tile1 {A0,B0,A1} (6) = 14 -> vmcnt(6)
// retires tile0.  Steady: +2 per phase (8/K-tile); gate at ph3 vmcnt(6)
// retires through B1(kt+1) = tile kt+1 resident; kt==NT-2 -> vmcnt(0).
// Overwrite liveness: each stage target's last reads are lgkm(0)-covered
// >=1 barrier before the stage (4 pairs hand-checked; same as qkv_fg).
// ---------------------------------------------------------------------------
__global__ __launch_bounds__(256, 1) void gemm_out_fg(
    const unsigned short* __restrict__ A, const unsigned short* __restrict__ B,
    const float* __restrict__ bias, float* __restrict__ C,
    int M, int N, int K) {
    __shared__ unsigned short Ls[2][16384];   // 2 x 32 KiB
    const int tid = threadIdx.x;
    const int wave = tid >> 6, lane = tid & 63;
    const int row16 = lane & 15, quad = lane >> 4;
    const int wrow = wave >> 1, wcol = wave & 1;     // 2 x 2 wave grid
    const int bm0 = blockIdx.y * 128, bn0 = blockIdx.x * 128;
    const int NT = K >> 6;

    floatx4 acc[4][4] = {};

    // stage one half: hf 0=A-ks0, 1=B-ks0, 2=A-ks1, 3=B-ks1 (4096 ushorts)
    auto stage_half = [&](int kt, int hf) {
        const bool isB = hf & 1;
        const unsigned short* mat = isB ? B : A;
        const int rbase = isB ? bn0 : bm0;
        const int colb = kt * 64 + (hf >> 1) * 32;
        unsigned short* dst = &Ls[kt & 1][hf * 4096];
        #pragma unroll
        for (int rd = 0; rd < 2; ++rd) {
            int g = tid + rd * 256;
            int rl = g & 7, c4 = (g >> 3) & 3, r8 = g >> 5;
            gl2lds16(mat + (size_t)(rbase + r8 * 8 + rl) * K + colb + c4 * 8,
                     dst + g * 8);
        }
    };

    // prologue: tile0 {A0,B0,A1,B1} + tile1 {A0,B0,A1}; retire tile0
    stage_half(0, 0); stage_half(0, 1); stage_half(0, 2); stage_half(0, 3);
    stage_half(1, 0); stage_half(1, 1); stage_half(1, 2);
    asm volatile("s_waitcnt vmcnt(6)" ::: "memory");
    __builtin_amdgcn_s_barrier();

    // per-thread fragment base offsets (ushorts within a half)
    const int ra = wrow * 64 + row16;
    const int rb = wcol * 64 + row16;
    const int aoff = (ra >> 3) * 256 + quad * 64 + (ra & 7) * 8;
    const int boff = (rb >> 3) * 256 + quad * 64 + (rb & 7) * 8;

    for (int kt = 0; kt < NT; ++kt) {
        const int bsel = kt & 1;
        bf16x8 af[4], bfr[4];
        // ---- phase 0: read A0[4]+B0[4]; stage B1(kt+1); MFMA nt{0,1} ----
        #pragma unroll
        for (int mt = 0; mt < 4; ++mt)
            af[mt] = *reinterpret_cast<const bf16x8*>(&Ls[bsel][aoff + mt * 512]);
        #pragma unroll
        for (int j = 0; j < 4; ++j)
            bfr[j] = *reinterpret_cast<const bf16x8*>(&Ls[bsel][4096 + boff + j * 512]);
        if (kt + 1 < NT) stage_half(kt + 1, 3);
        __builtin_amdgcn_s_barrier();
        asm volatile("s_waitcnt lgkmcnt(0)" ::: "memory");
        __builtin_amdgcn_sched_barrier(0);
        __builtin_amdgcn_s_setprio(1);
        #pragma unroll
        for (int mt = 0; mt < 4; ++mt) {
            acc[mt][0] = mfma16(af[mt], bfr[0], acc[mt][0]);
            acc[mt][1] = mfma16(af[mt], bfr[1], acc[mt][1]);
        }
        __builtin_amdgcn_s_setprio(0);
        __builtin_amdgcn_s_barrier();
        // ---- phase 1: stage A0(kt+2); MFMA nt{2,3} (frags held) ----
        if (kt + 2 < NT) stage_half(kt + 2, 0);
        __builtin_amdgcn_sched_barrier(0);
        __builtin_amdgcn_s_setprio(1);
        #pragma unroll
        for (int mt = 0; mt < 4; ++mt) {
            acc[mt][2] = mfma16(af[mt], bfr[2], acc[mt][2]);
            acc[mt][3] = mfma16(af[mt], bfr[3], acc[mt][3]);
        }
        __builtin_amdgcn_s_setprio(0);
        __builtin_amdgcn_s_barrier();
        // ---- phase 2: read A1[4]+B1[4]; stage B0(kt+2); MFMA nt{0,1} ----
        #pragma unroll
        for (int mt = 0; mt < 4; ++mt)
            af[mt] = *reinterpret_cast<const bf16x8*>(&Ls[bsel][8192 + aoff + mt * 512]);
        #pragma unroll
        for (int j = 0; j < 4; ++j)
            bfr[j] = *reinterpret_cast<const bf16x8*>(&Ls[bsel][12288 + boff + j * 512]);
        if (kt + 2 < NT) stage_half(kt + 2, 1);
        __builtin_amdgcn_s_barrier();
        asm volatile("s_waitcnt lgkmcnt(0)" ::: "memory");
        __builtin_amdgcn_sched_barrier(0);
        __builtin_amdgcn_s_setprio(1);
        #pragma unroll
        for (int mt = 0; mt < 4; ++mt) {
            acc[mt][0] = mfma16(af[mt], bfr[0], acc[mt][0]);
            acc[mt][1] = mfma16(af[mt], bfr[1], acc[mt][1]);
        }
        __builtin_amdgcn_s_setprio(0);
        __builtin_amdgcn_s_barrier();
        // ---- phase 3: stage A1(kt+2); GATE; MFMA nt{2,3} ----
        if (kt + 2 < NT) stage_half(kt + 2, 2);
        if (kt == NT - 2)     asm volatile("s_waitcnt vmcnt(0)" ::: "memory");
        else if (kt < NT - 2) asm volatile("s_waitcnt vmcnt(6)" ::: "memory");
        __builtin_amdgcn_sched_barrier(0);
        __builtin_amdgcn_s_setprio(1);
        #pragma unroll
        for (int mt = 0; mt < 4; ++mt) {
            acc[mt][2] = mfma16(af[mt], bfr[2], acc[mt][2]);
            acc[mt][3] = mfma16(af[mt], bfr[3], acc[mt][3]);
        }
        __builtin_amdgcn_s_setprio(0);
        __builtin_amdgcn_s_barrier();
    }

    // epilogue: bias + fp32 store
    #pragma unroll
    for (int mt = 0; mt < 4; ++mt) {
        #pragma unroll
        for (int nt = 0; nt < 4; ++nt) {
            int gc = bn0 + wcol * 64 + nt * 16 + row16;
            float bv = bias[gc];
            int gr0 = bm0 + wrow * 64 + mt * 16 + quad * 4;
            #pragma unroll
            for (int i = 0; i < 4; ++i)
                C[(size_t)(gr0 + i) * N + gc] = acc[mt][nt][i] + bv;
        }
    }
}

// ---------------------------------------------------------------------------
// tok GEMM split-K: C[2048,64] += gelu(P) @ [Bq;Bv]^T; C pre-zeroed.
// ---------------------------------------------------------------------------
template <int KSPLIT>
__global__ __launch_bounds__(256) void tok_gemm_splitk(
    const unsigned short* __restrict__ A0,
    const float* __restrict__ Bq, const float* __restrict__ Bv,
    float* __restrict__ C, int K) {
    constexpr int LDT = 72;
    __shared__ unsigned short As[64 * LDT];
    __shared__ unsigned short Bs[64 * LDT];
    const int tid = threadIdx.x;
    const int wave = tid >> 6, lane = tid & 63;
    const int row16 = lane & 15, quad = lane >> 4;
    const int wm = (wave >> 1) * 32, wn = (wave & 1) * 32;
    const int bm0 = blockIdx.y * 64;
    const int kbeg = blockIdx.x * KSPLIT;

    floatx4 acc[2][2] = {};

    for (int k0 = kbeg; k0 < kbeg + KSPLIT; k0 += 64) {
        #pragma unroll
        for (int it = 0; it < 2; ++it) {
            int i = tid + it * 256;
            int r = i >> 3, c8 = i & 7;
            size_t off = (size_t)(bm0 + r) * K + k0 + c8 * 8;
            ushort8v a0 = *reinterpret_cast<const ushort8v*>(A0 + off);
            ushort8v g;
            #pragma unroll
            for (int j = 0; j < 8; ++j) g[j] = f2b(gelu_f(b2f(a0[j])));
            *reinterpret_cast<ushort8v*>(&As[r * LDT + c8 * 8]) = g;

            const float* brow = (r < 32) ? (Bq + (size_t)r * K) : (Bv + (size_t)(r - 32) * K);
            float4 w0 = *reinterpret_cast<const float4*>(brow + k0 + c8 * 8);
            float4 w1 = *reinterpret_cast<const float4*>(brow + k0 + c8 * 8 + 4);
            ushort8v wb;
            wb[0] = f2b(w0.x); wb[1] = f2b(w0.y); wb[2] = f2b(w0.z); wb[3] = f2b(w0.w);
            wb[4] = f2b(w1.x); wb[5] = f2b(w1.y); wb[6] = f2b(w1.z); wb[7] = f2b(w1.w);
            *reinterpret_cast<ushort8v*>(&Bs[r * LDT + c8 * 8]) = wb;
        }
        __syncthreads();

        #pragma unroll
        for (int ks = 0; ks < 2; ++ks) {
            bf16x8 af[2], bfr[2];
            #pragma unroll
            for (int mt = 0; mt < 2; ++mt)
                af[mt] = *reinterpret_cast<const bf16x8*>(
                    &As[(wm + mt * 16 + row16) * LDT + ks * 32 + quad * 8]);
            #pragma unroll
            for (int nt = 0; nt < 2; ++nt)
                bfr[nt] = *reinterpret_cast<const bf16x8*>(
                    &Bs[(wn + nt * 16 + row16) * LDT + ks * 32 + quad * 8]);
            #pragma unroll
            for (int mt = 0; mt < 2; ++mt)
                #pragma unroll
                for (int nt = 0; nt < 2; ++nt)
                    acc[mt][nt] = mfma16(af[mt], bfr[nt], acc[mt][nt]);
        }
        __syncthreads();
    }

    #pragma unroll
    for (int mt = 0; mt < 2; ++mt)
        #pragma unroll
        for (int nt = 0; nt < 2; ++nt) {
            int gc = wn + nt * 16 + row16;
            int gr0 = bm0 + wm + mt * 16 + quad * 4;
            #pragma unroll
            for (int i = 0; i < 4; ++i)
                atomicAdd(&C[(size_t)(gr0 + i) * 64 + gc], acc[mt][nt][i]);
        }
}

// ---------------------------------------------------------------------------
// tau gating + RoPE + layout transforms; qkv = P (bf16, bias included).
// V is packed fragment-ordered: vpk[h][sb32][nt][quad][m][8] where
// element = V[d=nt*16+m][s=sb*32+quad*8+j] -> attn B-frag load is
// base + lane*16B (fully coalesced). q pre-scaled by 0.125*log2e.
// ---------------------------------------------------------------------------
__global__ __launch_bounds__(256) void qkv_process(
    const unsigned short* __restrict__ P,
    const float* __restrict__ tok_raw, const float* __restrict__ tau_alpha,
    const int* __restrict__ positions, unsigned short* __restrict__ qh,
    unsigned short* __restrict__ kh, unsigned short* __restrict__ vpk) {
    const int h = blockIdx.y;
    const int t0 = blockIdx.x * 64;
    const int tid = threadIdx.x;
    __shared__ float vtr[64][65];
    __shared__ float tauq_s[64], tauv_s[64];

    if (tid < 64) {
        int t = t0 + tid;
        float pos = (float)positions[t];
        float pl = logf(fmaxf(pos + 1.0f, 1e-6f));
        float a = tau_alpha[h];
        float tp = 0.5f + 1.0f / (1.0f + __expf(-a * pl));
        tauq_s[tid] = tanhf(tok_raw[t * 64 + h]) + tp;
        tauv_s[tid] = tanhf(tok_raw[t * 64 + 32 + h]) + tp;
    }
    __syncthreads();

    const float QSCALE = 0.18033688011112042f;   // 0.125 * log2(e)
    #pragma unroll
    for (int it = 0; it < 2; ++it) {
        int idx = tid + it * 256;
        int tl = idx >> 3, c8 = idx & 7;
        int t = t0 + tl;
        size_t rb = (size_t)t * 6144 + h * 64 + c8 * 8;
        ushort8v q0v = *reinterpret_cast<const ushort8v*>(P + rb);
        ushort8v k0v = *reinterpret_cast<const ushort8v*>(P + rb + 2048);
        ushort8v v0v = *reinterpret_cast<const ushort8v*>(P + rb + 4096);
        float tq = tauq_s[tl], tv = tauv_s[tl];
        float qo[8], ko[8];
        #pragma unroll
        for (int j = 0; j < 8; ++j) {
            qo[j] = b2f(q0v[j]) * tq;
            ko[j] = b2f(k0v[j]);
        }
        if (c8 < 4) {                          // rotary chunks 0..3
            size_t rp = (size_t)t * 6144 + h * 64 + (c8 ^ 2) * 8;
            ushort8v qp0 = *reinterpret_cast<const ushort8v*>(P + rp);
            ushort8v kp0 = *reinterpret_cast<const ushort8v*>(P + rp + 2048);
            float pos = (float)positions[t];
            float sgn = (c8 < 2) ? -1.0f : 1.0f;
            #pragma unroll
            for (int j = 0; j < 8; ++j) {
                int fi = (c8 * 8 + j) & 15;
                float ang = pos * INV_FREQ[fi];
                float s, c;
                sincosf(ang, &s, &c);
                float qp = b2f(qp0[j]) * tq;
                float kp = b2f(kp0[j]);
                qo[j] = qo[j] * c + sgn * qp * s;
                ko[j] = ko[j] * c + sgn * kp * s;
            }
        }
        size_t ob = ((size_t)h * 2048 + t) * 64 + c8 * 8;
        ushort8v qw, kw;
        #pragma unroll
        for (int j = 0; j < 8; ++j) {
            qw[j] = f2b(qo[j] * QSCALE);
            kw[j] = f2b(ko[j]);
        }
        *reinterpret_cast<ushort8v*>(qh + ob) = qw;
        *reinterpret_cast<ushort8v*>(kh + ob) = kw;
        #pragma unroll
        for (int j = 0; j < 8; ++j)
            vtr[c8 * 8 + j][tl] = b2f(v0v[j]) * tv;
    }
    __syncthreads();
    // V pack: vpk[h][sb32][nt][quad][m][8] = V[d=nt*16+m][s=sb*32+quad*8+j]
    #pragma unroll
    for (int it = 0; it < 2; ++it) {
        int idx = tid + it * 256;
        int d = idx >> 3, tc = (idx & 7) * 8;      // s-chunk [t0+tc, t0+tc+8)
        int sb = (t0 + tc) >> 5;
        int quad = (tc & 31) >> 3;
        int nt = d >> 4, m = d & 15;
        ushort8v w;
        #pragma unroll
        for (int j = 0; j < 8; ++j) w[j] = f2b(vtr[d][tc + j]);
        *reinterpret_cast<ushort8v*>(
            vpk + (size_t)h * 131072 + sb * 2048 + nt * 512 + quad * 128 + m * 8) = w;
    }
}

// ---------------------------------------------------------------------------
// s-split MAX-FREE flash attention, XCD-affine 1D schedule (R9 config).
// b&7 = XCD slot; head = (b&7) + 8*((b>>3)&3) -> 4 heads per XCD. cpos=b>>5
// walks 40 chunks longest-first. Wave owns 32 q-rows (2 m-frags).
// P = 2^s directly (scale folded into qh); masked -> 0.
// R18 (verified R11): bk[4][2]/bv[4] register arrays force all K/V loads
// issued up-front + counted-vmcnt drain under MFMA; setprio on clusters.
// ---------------------------------------------------------------------------
__global__ __launch_bounds__(256) void attn_fa(
    const unsigned short* __restrict__ qh, const unsigned short* __restrict__ kh,
    const unsigned short* __restrict__ vpk, unsigned short* __restrict__ Opart,
    float* __restrict__ ml) {
    constexpr int LD = 72;
    __shared__ unsigned short pbuf[4][2][16 * LD];   // [wave][mt]
    const int b = blockIdx.x;
    const int h = (b & 7) + 8 * ((b >> 3) & 3);
    const int cpos = b >> 5;
    const int qt = CHUNK_QT[cpos], ch = CHUNK_C[cpos];
    const int q0 = qt * 128;
    const int slot = (h * 16 + qt) * 4 + ch;
    const int wave = threadIdx.x >> 6, lane = threadIdx.x & 63;
    const int m = lane & 15, quad = lane >> 4;
    const int qrow0 = q0 + wave * 32;
    const int sbeg = ch * 512;
    const int send = min(sbeg + 512, qrow0 + 32);

    bf16x8 aq[2][2];
    #pragma unroll
    for (int mt = 0; mt < 2; ++mt) {
        const unsigned short* qptr = qh + ((size_t)h * 2048 + qrow0 + mt * 16 + m) * 64;
        aq[mt][0] = *reinterpret_cast<const bf16x8*>(qptr + quad * 8);
        aq[mt][1] = *reinterpret_cast<const bf16x8*>(qptr + 32 + quad * 8);
    }
    const unsigned short* kbase = kh + (size_t)h * 2048 * 64;
    const unsigned short* vbase = vpk + (size_t)h * 131072;

    floatx4 o[2][4] = {};
    float lsum[2][4] = {};

    for (int s0 = sbeg; s0 < send; s0 += 64) {
        // ---- K loads: all 8 b128 issued up-front (bk[4][2] held in regs) ----
        bf16x8 bk[4][2];
        #pragma unroll
        for (int sg = 0; sg < 4; ++sg) {
            const unsigned short* kr = kbase + (size_t)(s0 + sg * 16 + m) * 64;
            bk[sg][0] = *reinterpret_cast<const bf16x8*>(kr + quad * 8);
            bk[sg][1] = *reinterpret_cast<const bf16x8*>(kr + 32 + quad * 8);
        }
        floatx4 sc[2][4];
        __builtin_amdgcn_s_setprio(1);
        #pragma unroll
        for (int sg = 0; sg < 4; ++sg) {
            #pragma unroll
            for (int mt = 0; mt < 2; ++mt) {
                floatx4 z = {};
                z = mfma16(aq[mt][0], bk[sg][0], z);
                z = mfma16(aq[mt][1], bk[sg][1], z);
                sc[mt][sg] = z;
            }
        }
        __builtin_amdgcn_s_setprio(0);
        if (s0 + 63 > qrow0) {               // only near-diagonal steps mask
            #pragma unroll
            for (int mt = 0; mt < 2; ++mt)
                #pragma unroll
                for (int sg = 0; sg < 4; ++sg)
                    #pragma unroll
                    for (int i = 0; i < 4; ++i) {
                        int t = qrow0 + mt * 16 + quad * 4 + i;
                        int s = s0 + sg * 16 + m;
                        sc[mt][sg][i] = (s > t) ? -1e30f : sc[mt][sg][i];
                    }
        }
        // P = 2^s directly (max-free, scale pre-folded); masked -> 0
        #pragma unroll
        for (int mt = 0; mt < 2; ++mt)
            #pragma unroll
            for (int sg = 0; sg < 4; ++sg)
                #pragma unroll
                for (int i = 0; i < 4; ++i)
                    sc[mt][sg][i] = fexp2(sc[mt][sg][i]);
        #pragma unroll
        for (int mt = 0; mt < 2; ++mt)
            #pragma unroll
            for (int i = 0; i < 4; ++i)
                lsum[mt][i] += (sc[mt][0][i] + sc[mt][1][i]) + (sc[mt][2][i] + sc[mt][3][i]);

        // P: C-layout regs -> wave-private LDS -> A-layout frags (no barrier)
        unsigned short* pb0 = pbuf[wave][0];
        unsigned short* pb1 = pbuf[wave][1];
        #pragma unroll
        for (int sg = 0; sg < 4; ++sg)
            #pragma unroll
            for (int i = 0; i < 4; ++i) {
                pb0[(quad * 4 + i) * LD + sg * 16 + m] = f2b_trunc(sc[0][sg][i]);
                pb1[(quad * 4 + i) * LD + sg * 16 + m] = f2b_trunc(sc[1][sg][i]);
            }
        bf16x8 ap[2][2];
        #pragma unroll
        for (int mt = 0; mt < 2; ++mt) {
            ap[mt][0] = *reinterpret_cast<const bf16x8*>(&pbuf[wave][mt][m * LD + quad * 8]);
            ap[mt][1] = *reinterpret_cast<const bf16x8*>(&pbuf[wave][mt][m * LD + 32 + quad * 8]);
        }
        #pragma unroll
        for (int c = 0; c < 2; ++c) {
            const unsigned short* vrow = vbase + ((s0 >> 5) + c) * 2048;
            bf16x8 bv[4];
            #pragma unroll
            for (int nt = 0; nt < 4; ++nt)
                bv[nt] = *reinterpret_cast<const bf16x8*>(vrow + nt * 512 + lane * 8);
            __builtin_amdgcn_s_setprio(1);
            #pragma unroll
            for (int nt = 0; nt < 4; ++nt) {
                o[0][nt] = mfma16(ap[0][c], bv[nt], o[0][nt]);
                o[1][nt] = mfma16(ap[1][c], bv[nt], o[1][nt]);
            }
            __builtin_amdgcn_s_setprio(0);
        }
    }

    // epilogue: reduce l across the 16 column-lanes, store partials
    #pragma unroll
    for (int d = 1; d < 16; d <<= 1)
        #pragma unroll
        for (int mt = 0; mt < 2; ++mt)
            #pragma unroll
            for (int i = 0; i < 4; ++i)
                lsum[mt][i] += __shfl_xor(lsum[mt][i], d, 16);
    #pragma unroll
    for (int mt = 0; mt < 2; ++mt) {
        #pragma unroll
        for (int nt = 0; nt < 4; ++nt)
            #pragma unroll
            for (int i = 0; i < 4; ++i)
                Opart[((size_t)slot * 128 + wave * 32 + mt * 16 + quad * 4 + i) * 64 + nt * 16 + m]
                    = f2b(o[mt][nt][i]);
        if (m == 0) {
            #pragma unroll
            for (int i = 0; i < 4; ++i)
                ml[(size_t)slot * 128 + wave * 32 + mt * 16 + quad * 4 + i] = lsum[mt][i];
        }
    }
}

// ---------------------------------------------------------------------------
// Merge s-split partials (max-free): O = sum_c O~_c / sum_c l_c.
// Block = (qt, h); thread t: row t/2, cols (t&1)*32 .. +32.
// ---------------------------------------------------------------------------
__global__ __launch_bounds__(256) void attn_merge(
    const unsigned short* __restrict__ Opart, const float* __restrict__ ml,
    unsigned short* __restrict__ attnb) {
    const int qt = blockIdx.x, h = blockIdx.y;
    const int nc = qt / 4 + 1;
    const int tid = threadIdx.x;
    const int r = tid >> 1, dh = (tid & 1) * 32;
    const int bs = (h * 16 + qt) * 4;

    float denom = 0.0f;
    #pragma unroll
    for (int c = 0; c < 4; ++c)
        if (c < nc) denom += ml[(size_t)(bs + c) * 128 + r];
    float inv = 1.0f / denom;

    float acc[32] = {};
    #pragma unroll
    for (int c = 0; c < 4; ++c) {
        if (c < nc) {
            const unsigned short* op = Opart + ((size_t)(bs + c) * 128 + r) * 64 + dh;
            #pragma unroll
            for (int j = 0; j < 4; ++j) {
                ushort8v v = *reinterpret_cast<const ushort8v*>(op + j * 8);
                #pragma unroll
                for (int k = 0; k < 8; ++k)
                    acc[j * 8 + k] += b2f(v[k]);
            }
        }
    }
    unsigned short* dst = attnb + (size_t)(qt * 128 + r) * 2048 + h * 64 + dh;
    #pragma unroll
    for (int j = 0; j < 4; ++j) {
        ushort8v v;
        #pragma unroll
        for (int k = 0; k < 8; ++k) v[k] = f2b(acc[j * 8 + k] * inv);
        *reinterpret_cast<ushort8v*>(dst + j * 8) = v;
    }
}

// ---------------------------------------------------------------------------
extern "C" void kernel_launch(void* const* d_in, const int* in_sizes, int n_in,
                              void* d_out, int out_size, void* d_ws, size_t ws_size,
                              hipStream_t stream) {
    const int*   positions = (const int*)d_in[0];
    const float* hidden    = (const float*)d_in[1];
    const float* Wqkv      = (const float*)d_in[2];
    const float* bqkv      = (const float*)d_in[3];
    const float* Wout      = (const float*)d_in[4];
    const float* bout      = (const float*)d_in[5];
    const float* tau_alpha = (const float*)d_in[6];
    const float* tau_wq    = (const float*)d_in[7];
    const float* tau_wv    = (const float*)d_in[8];

    unsigned char* ws = (unsigned char*)d_ws;
    unsigned short* P       = (unsigned short*)(ws);             // 25165824
    unsigned short* Opart   = (unsigned short*)(ws);             // reuses P (33.5MB)
    unsigned short* wqb     = (unsigned short*)(ws + 50331648);  // dead after GEMM1
    unsigned short* qh      = (unsigned short*)(ws + 50331648);
    unsigned short* kh      = (unsigned short*)(ws + 58720256);
    unsigned short* vpk     = (unsigned short*)(ws + 67108864);
    unsigned short* hb      = (unsigned short*)(ws + 75497472);  // dead after GEMM1
    float*          tok_raw = (float*)(ws + 75497472);           // after hb dead
    unsigned short* attnb   = (unsigned short*)(ws + 75497472);  // after tok_raw dead
    float*          ml      = (float*)(ws + 83886080);
    unsigned short* wob     = (unsigned short*)(ws + 85983232);

    // 0) fp32 -> bf16 conversions (one launch, 3 segments)
    cvt3_f32_bf16<<<10240, 256, 0, stream>>>(
        hidden, hb, 524288, Wqkv, wqb, 1572864, Wout, wob, 524288);
    // 1) QKV GEMM 256x192 tile, grid 32x8 = 256 blocks = full CU fill
    gemm_qkv_fg<<<dim3(32, 8), 512, 0, stream>>>(
        hb, wqb, bqkv, P, 2048, 6144, 2048);
    // 2) tok_raw = gelu(P) @ [tau_wq;tau_wv]^T  (split-K + atomics)
    hipMemsetAsync(tok_raw, 0, (size_t)2048 * 64 * 4, stream);
    tok_gemm_splitk<256><<<dim3(24, 32), 256, 0, stream>>>(
        P, tau_wq, tau_wv, tok_raw, 6144);
    // 3) gating + RoPE + layouts (vectorized; V fragment-packed)
    qkv_process<<<dim3(32, 32), 256, 0, stream>>>(
        P, tok_raw, tau_alpha, positions, qh, kh, vpk);
    // 4) s-split max-free flash attention, XCD-affine (1280 blocks)
    attn_fa<<<1280, 256, 0, stream>>>(qh, kh, vpk, Opart, ml);
    // 5) merge partials -> attnb
    attn_merge<<<dim3(16, 32), 256, 0, stream>>>(Opart, ml, attnb);
    // 6) out = attnb @ wob^T + bout  (fg schedule, 128^2 tile, 256 blocks)
    gemm_out_fg<<<dim3(16, 16), 256, 0, stream>>>(
        attnb, wob, bout, (float*)d_out, 2048, 2048, 2048);
}